// Round 14
// baseline (606.262 us; speedup 1.0000x reference)
//
#include <hip/hip_runtime.h>

typedef unsigned short u16;
typedef __attribute__((ext_vector_type(8))) short short8;
typedef __attribute__((ext_vector_type(4))) float f32x4;

#define B_   2
#define N_   5
#define K_   5
#define Q_   4
#define T_   5
#define D_   768
#define L_   128
#define BN_  (B_*N_)            // 10
#define BNK_ (B_*N_*K_)         // 50
#define BQ_  (B_*N_*Q_*N_)      // 200
#define K4_  (4*D_)             // 3072
#define KFQ  1536               // fuse K in main GEMM (chunks 2,3 only)
#define AROWS 144               // 128 query + 5 es + 11 pad

#define QEMB_N  (40*128*768)    // 3,932,160
#define PROJW_N (768*3072)      // 2,359,296
// A_all row map: [0,5120) qemb | [5120,5170) proto | [5170,5248) zero
//                [5248,6248) sup | [6248,6298) proto | [6298,6400) zero
#define R_PROTO1 5120
#define R_SUP    5248
#define R_PROTO2 6248
#define R_TOTAL  6400

__device__ __forceinline__ float bf2f(u16 u) {
    return __uint_as_float(((unsigned)u) << 16);
}
__device__ __forceinline__ u16 f2bf(float f) {
    unsigned u = __float_as_uint(f);
    return (u16)((u + 0x7fffu + ((u >> 16) & 1u)) >> 16);
}
// async global->LDS, 16B per lane; lds base wave-uniform (HW adds lane*16)
__device__ __forceinline__ void gl_lds16(const u16* g, u16* l) {
    __builtin_amdgcn_global_load_lds(
        (const __attribute__((address_space(1))) unsigned int*)g,
        (__attribute__((address_space(3))) unsigned int*)l, 16, 0, 0);
}

// ---------------- K0: convert qemb (-> A_all rows 0..5119) / projw / relw1 ----------------
__global__ void k_convert3(const float* __restrict__ q, const float* __restrict__ pw,
                           const float* __restrict__ rw, u16* __restrict__ qo,
                           u16* __restrict__ po, u16* __restrict__ ro) {
    const long n1 = QEMB_N / 4, n2 = PROJW_N / 4;
    const long total = n1 + 2 * n2;
    for (long i = (long)blockIdx.x * 256 + threadIdx.x; i < total; i += (long)gridDim.x * 256) {
        const float* src; u16* dst; long k;
        if (i < n1)            { src = q;  dst = qo; k = i; }
        else if (i < n1 + n2)  { src = pw; dst = po; k = i - n1; }
        else                   { src = rw; dst = ro; k = i - n1 - n2; }
        float4 v = ((const float4*)src)[k];
        u16 o[4] = {f2bf(v.x), f2bf(v.y), f2bf(v.z), f2bf(v.w)};
        *(uint2*)(dst + k * 4) = *(const uint2*)o;
    }
}

// ---------------- K1: per-shot tag prototypes (segment-parallel) ----------------
__global__ void k_proto_shot(const float* __restrict__ label, const float* __restrict__ smask,
                             const float* __restrict__ semb, float* __restrict__ proto_shot) {
    int bnk = blockIdx.x;
    int s = blockIdx.y;                       // segment 0..2 (256 d's each)
    __shared__ int   s_tag[L_];
    __shared__ float s_w[L_];
    __shared__ float s_cnt[T_];
    int tid = threadIdx.x;
    if (tid < L_) {
        const float* lp = label + ((long)bnk * L_ + tid) * T_;
        float best = lp[0]; int bi = 0;
        #pragma unroll
        for (int t = 1; t < T_; ++t) { float v = lp[t]; if (v > best) { best = v; bi = t; } }
        s_tag[tid] = bi;
        s_w[tid]   = (bi == 0) ? smask[(long)bnk * L_ + tid] : 1.0f;
    }
    __syncthreads();
    if (tid < T_) {
        float c = 0.f;
        for (int l = 0; l < L_; ++l) if (s_tag[l] == tid) c += s_w[l];
        s_cnt[tid] = c;
    }
    __syncthreads();
    float acc[T_] = {};
    for (int l = 0; l < L_; ++l) {
        float w = s_w[l]; int tg = s_tag[l];
        float e = semb[((long)bnk * L_ + l) * D_ + tid + s * 256] * w;
        #pragma unroll
        for (int t = 0; t < T_; ++t) acc[t] += (tg == t) ? e : 0.0f;
    }
    int d = tid + s * 256;
    #pragma unroll
    for (int t = 0; t < T_; ++t) {
        float c = s_cnt[t];
        float v = (c > 0.f) ? acc[t] / fmaxf(c, 1.f) : 0.f;
        proto_shot[(bnk * T_ + t) * D_ + d] = v;
    }
}

// ---------------- K1b: mean over K shots -> proto_f32 + A_all proto rows + zero pads ----------------
__global__ void k_proto_mean(const float* __restrict__ proto_shot,
                             float* __restrict__ proto_f32, u16* __restrict__ A_all) {
    int bx = blockIdx.x;
    if (bx < 150) {
        int idx = bx * 256 + threadIdx.x;
        if (idx >= BN_ * T_ * D_) return;
        int r = idx / D_, d = idx - r * D_;
        int bn = r / T_;
        int rem = idx - bn * (T_ * D_);
        float s = 0.f;
        #pragma unroll
        for (int k = 0; k < K_; ++k) s += proto_shot[(bn * K_ + k) * (T_ * D_) + rem];
        s *= (1.f / K_);
        proto_f32[idx] = s;
        u16 b = f2bf(s);
        A_all[(size_t)(R_PROTO1 + r) * D_ + d] = b;
        A_all[(size_t)(R_PROTO2 + r) * D_ + d] = b;
    } else {
        // zero pad rows: [5170,5248) = 59904 elems, then [6298,6400) = 78336 elems
        int zidx = (bx - 150) * 256 + threadIdx.x;
        if (zidx >= 59904 + 78336) return;
        size_t off;
        if (zidx < 59904) off = (size_t)5170 * D_ + zidx;
        else              off = (size_t)6298 * D_ + (zidx - 59904);
        A_all[off] = 0;
    }
}

// ---------------- K2: co-attention -> qf (chunks 2,3), sup rows of A_all, p2m, qssum ----------------
__global__ void k_attn(const float* __restrict__ qemb, const float* __restrict__ qmask_g,
                       const float* __restrict__ proto_f32,
                       u16* __restrict__ qf, u16* __restrict__ supA,
                       float* __restrict__ p2m_ws, float* __restrict__ qssum_ws) {
    int x = blockIdx.x;
    int xcd = x & 7, slot = x >> 3;
    int g = (slot / 5) * 8 + xcd;           // q_idx 0..39
    int n2 = slot % 5;
    int bq = g * 5 + n2;
    int q_idx = g;
    int bn = (bq / (N_ * Q_ * N_)) * N_ + (bq % N_);
    __shared__ float s_proto[T_ * D_];
    __shared__ float s_att[T_][L_];
    __shared__ float s_ps[T_][L_];
    __shared__ float s_p2[L_][8];
    __shared__ float s_qm[L_];
    int tid = threadIdx.x;
    int w = tid >> 6, lane = tid & 63;
    for (int i = tid; i < T_ * D_; i += 256) s_proto[i] = proto_f32[bn * T_ * D_ + i];
    if (tid < L_) s_qm[tid] = qmask_g[(long)q_idx * L_ + tid];
    __syncthreads();
    for (int p = tid; p < T_ * L_; p += 256) {
        int t = p >> 7, q = p & (L_ - 1);
        const float* pp = s_proto + t * D_;
        const float4* qp = (const float4*)(qemb + ((size_t)q_idx * L_ + q) * D_);
        float acc = 0.f;
        #pragma unroll 4
        for (int d = 0; d < D_ / 4; ++d) {
            float4 v = qp[d];
            acc += v.x * pp[4 * d] + v.y * pp[4 * d + 1] + v.z * pp[4 * d + 2] + v.w * pp[4 * d + 3];
        }
        s_att[t][q] = acc + 100.f * s_qm[q];
    }
    __syncthreads();
    if (tid < T_) {                       // softmax over q (support path)
        int t = tid; float m = -1e30f;
        for (int q = 0; q < L_; ++q) m = fmaxf(m, s_att[t][q]);
        float ss = 0.f;
        for (int q = 0; q < L_; ++q) { float e = __expf(s_att[t][q] - m); s_ps[t][q] = e; ss += e; }
        float inv = 1.f / ss;
        for (int q = 0; q < L_; ++q) s_ps[t][q] *= inv;
    } else if (tid >= 128) {              // softmax over t (query path) -> masked weights
        int q = tid - 128; float m = -1e30f;
        float e[T_];
        #pragma unroll
        for (int t = 0; t < T_; ++t) m = fmaxf(m, s_att[t][q]);
        float ss = 0.f;
        #pragma unroll
        for (int t = 0; t < T_; ++t) { e[t] = __expf(s_att[t][q] - m); ss += e[t]; }
        float inv = s_qm[q] / ss;
        #pragma unroll
        for (int t = 0; t < T_; ++t) {
            s_p2[q][t] = e[t] * inv;
            p2m_ws[((size_t)bq * T_ + t) * L_ + q] = e[t] * inv;
        }
    } else if (tid == 5) {
        float s = 0.f;
        for (int q = 0; q < L_; ++q) s += s_qm[q];
        qssum_ws[bq] = s;
    }
    __syncthreads();
    u16* qfb = qf + (size_t)bq * AROWS * KFQ;
    {   // support_[t] -> A_all sup rows (bf16) + es rows 128..132 of qf (chunks 2,3)
        float acc[T_][3] = {};
        #pragma unroll 4
        for (int q = 0; q < L_; ++q) {
            const float* qp = qemb + ((size_t)q_idx * L_ + q) * D_;
            float qv[3];
            #pragma unroll
            for (int s = 0; s < 3; ++s) qv[s] = qp[tid + s * 256];
            #pragma unroll
            for (int t = 0; t < T_; ++t) {
                float p = s_ps[t][q];
                #pragma unroll
                for (int s = 0; s < 3; ++s) acc[t][s] += p * qv[s];
            }
        }
        #pragma unroll
        for (int t = 0; t < T_; ++t) {
            u16* er = qfb + (size_t)(128 + t) * KFQ;
            #pragma unroll
            for (int s = 0; s < 3; ++s) {
                int d = tid + s * 256;
                float p = s_proto[t * D_ + d];
                float sv = acc[t][s];
                supA[((size_t)bq * T_ + t) * D_ + d] = f2bf(sv);
                er[d]       = f2bf(fabsf(p - sv));
                er[768 + d] = f2bf(p * sv);
            }
        }
    }
    // query rows 0..127: wave per row; scalar lane-consecutive LDS reads (conflict-free),
    // coalesced 128B stores, zero barriers.
    for (int rr = 0; rr < 32; ++rr) {
        int row = w * 32 + rr;
        float p0 = s_p2[row][0], p1 = s_p2[row][1], p2v = s_p2[row][2];
        float p3 = s_p2[row][3], p4 = s_p2[row][4];
        const float* qrow = qemb + ((size_t)q_idx * L_ + row) * D_;
        u16* qr = qfb + (size_t)row * KFQ;
        #pragma unroll
        for (int ch = 0; ch < 12; ++ch) {
            int c = ch * 64 + lane;
            float m2 = p0 * s_proto[c] + p1 * s_proto[D_ + c] + p2v * s_proto[2 * D_ + c]
                     + p3 * s_proto[3 * D_ + c] + p4 * s_proto[4 * D_ + c];
            float qv = qrow[c];
            qr[c]       = f2bf(fabsf(qv - m2));
            qr[768 + c] = f2bf(qv * m2);
        }
    }
    {   // zero pad rows 133..143
        u16* pr2 = qfb + (size_t)133 * KFQ;
        short8 z = short8{0, 0, 0, 0, 0, 0, 0, 0};
        for (int i = tid; i < (11 * KFQ) / 8; i += 256) *(short8*)(pr2 + i * 8) = z;
    }
}

// ---------------- K3: combined G1+W2 GEMM: A_all(6400x768) @ projw(chunk0|chunk1)^T ----------------
#define SUBGW ((128 + 128) * 32)            // one 32-k sub-tile (A128+B128) in u16
__global__ __launch_bounds__(256) void k_gemm_gw(const u16* __restrict__ A_all,
                                                 const u16* __restrict__ projw_bf,
                                                 u16* __restrict__ g1, u16* __restrict__ sw2,
                                                 u16* __restrict__ pw2) {
    int mbase = blockIdx.y * 128;
    int jbase = blockIdx.x * 128;
    int boff = (mbase >= R_SUP) ? 768 : 0;
    __shared__ __align__(16) u16 sT[2][2 * SUBGW];
    int tid = threadIdx.x;
    int lane = tid & 63, w = tid >> 6, quad = lane >> 4, l16 = lane & 15;
    int srow = lane >> 2, sko = lane & 3;
    const u16* Ab = A_all + ((size_t)mbase + srow) * D_ + sko * 8;
    const u16* Bb = projw_bf + (size_t)(jbase + srow) * K4_ + boff + sko * 8;

    f32x4 zero = {0.f, 0.f, 0.f, 0.f};
    f32x4 acc[8][2];
    #pragma unroll
    for (int rt = 0; rt < 8; ++rt) { acc[rt][0] = zero; acc[rt][1] = zero; }

    auto issue = [&](int kt, int b) {
        #pragma unroll
        for (int s = 0; s < 2; ++s) {
            int k0 = kt * 64 + s * 32;
            u16* base = sT[b] + s * SUBGW;
            gl_lds16(Ab + (size_t)(w * 16) * D_ + k0, base + (w * 16) * 32);
            gl_lds16(Ab + (size_t)(64 + w * 16) * D_ + k0, base + (64 + w * 16) * 32);
            gl_lds16(Bb + (size_t)(w * 16) * K4_ + k0, base + (128 + w * 16) * 32);
            gl_lds16(Bb + (size_t)(64 + w * 16) * K4_ + k0, base + (128 + 64 + w * 16) * 32);
        }
    };

    issue(0, 0);
    for (int kt = 0; kt < D_ / 64; ++kt) {           // 12 iterations
        int cur = kt & 1;
        __syncthreads();
        if (kt + 1 < D_ / 64) issue(kt + 1, 1 - cur);
        #pragma unroll
        for (int s = 0; s < 2; ++s) {
            const u16* base = sT[cur] + s * SUBGW;
            short8 bfr[2];
            #pragma unroll
            for (int jj = 0; jj < 2; ++jj)
                bfr[jj] = *(const short8*)(base + (128 + (w * 2 + jj) * 16 + l16) * 32 + quad * 8);
            #pragma unroll
            for (int rt = 0; rt < 8; ++rt) {
                short8 a = *(const short8*)(base + (rt * 16 + l16) * 32 + quad * 8);
                acc[rt][0] = __builtin_amdgcn_mfma_f32_16x16x32_bf16(a, bfr[0], acc[rt][0], 0, 0, 0);
                acc[rt][1] = __builtin_amdgcn_mfma_f32_16x16x32_bf16(a, bfr[1], acc[rt][1], 0, 0, 0);
            }
        }
    }
    #pragma unroll
    for (int jj = 0; jj < 2; ++jj) {
        int col = jbase + (w * 2 + jj) * 16 + l16;
        #pragma unroll
        for (int rt = 0; rt < 8; ++rt)
            #pragma unroll
            for (int r = 0; r < 4; ++r) {
                int row = mbase + rt * 16 + quad * 4 + r;
                u16 v = f2bf(acc[rt][jj][r]);
                if (row < R_SUP)            g1[(size_t)row * D_ + col] = v;
                else if (row < R_PROTO2)    sw2[(size_t)(row - R_SUP) * D_ + col] = v;
                else if (row < R_PROTO2+50) pw2[(size_t)(row - R_PROTO2) * D_ + col] = v;
            }
    }
}

// ---------------- K4: main GEMM — barrier-free direct-to-register fragments ----------------
// grid 1200 swizzled (attn-matched XCD map). Per wave per 32-k: 9 A-frag + 2 B-frag
// global_load_dwordx4 (each lane 16B; quads of a row cover contiguous 64B => full lines),
// software-pipelined x2 in registers. NO LDS staging, NO K-loop barriers.
__global__ __launch_bounds__(256) void k_gemm_q(
        const u16* __restrict__ qf, const u16* __restrict__ projw_bf,
        const float* __restrict__ projb, const u16* __restrict__ g1,
        const u16* __restrict__ pw2, const u16* __restrict__ sw2,
        const float* __restrict__ p2m, const float* __restrict__ qssum_ws,
        u16* __restrict__ cat_ws) {
    int x = blockIdx.x;
    int xcd = x & 7, slot = x >> 3;          // slot 0..149
    int i = slot / 6, jslot = slot % 6;
    int g = (i / 5) * 8 + xcd;               // q-group 0..39, same map as k_attn
    int bq = g * 5 + (i % 5);
    int jbase = jslot * 128;
    int q_idx = bq / N_;
    int bn = (bq / (N_ * Q_ * N_)) * N_ + (bq % N_);
    __shared__ float s_p2mL[T_ * 128];
    __shared__ float s_pw2L[T_ * 128];
    int tid = threadIdx.x;
    int lane = tid & 63, w = tid >> 6, quad = lane >> 4, l16 = lane & 15;

    // per-lane fragment bases: A frag rt at Abase + rt*16*KFQ + kt*32 ; B frag jj at Bbase + jj*16*K4_
    const u16* Abase = qf + ((size_t)bq * AROWS + l16) * KFQ + quad * 8;
    const u16* Bbase = projw_bf + (size_t)(jbase + w * 32 + l16) * K4_ + 1536 + quad * 8;

    f32x4 zero = {0.f, 0.f, 0.f, 0.f};
    f32x4 acc[9][2];
    #pragma unroll
    for (int rt = 0; rt < 9; ++rt) { acc[rt][0] = zero; acc[rt][1] = zero; }

    short8 a0[9], b0[2], a1[9], b1[2];
    auto loadf = [&](short8* A, short8* Bf, int kt) {
        int k0 = kt * 32;
        #pragma unroll
        for (int rt = 0; rt < 9; ++rt)
            A[rt] = *(const short8*)(Abase + (size_t)rt * 16 * KFQ + k0);
        #pragma unroll
        for (int jj = 0; jj < 2; ++jj)
            Bf[jj] = *(const short8*)(Bbase + (size_t)jj * 16 * K4_ + k0);
    };
    auto domfma = [&](short8* A, short8* Bf) {
        #pragma unroll
        for (int rt = 0; rt < 9; ++rt) {
            acc[rt][0] = __builtin_amdgcn_mfma_f32_16x16x32_bf16(A[rt], Bf[0], acc[rt][0], 0, 0, 0);
            acc[rt][1] = __builtin_amdgcn_mfma_f32_16x16x32_bf16(A[rt], Bf[1], acc[rt][1], 0, 0, 0);
        }
    };

    loadf(a0, b0, 0);
    for (int kt = 0; kt < KFQ / 32; kt += 2) {       // 24 iterations of 2 sub-tiles
        loadf(a1, b1, kt + 1);
        domfma(a0, b0);
        if (kt + 2 < KFQ / 32) loadf(a0, b0, kt + 2);
        domfma(a1, b1);
    }
    // epilogue staging: p2m + pw2 slices for this (bq, j) block
    for (int i2 = tid; i2 < T_ * 128; i2 += 256) {
        s_p2mL[i2] = p2m[(size_t)bq * (T_ * 128) + i2];
        s_pw2L[i2] = bf2f(pw2[(size_t)(bn * T_ + (i2 >> 7)) * D_ + jbase + (i2 & 127)]);
    }
    __syncthreads();
    float inv_qs = 1.f / qssum_ws[bq];
    #pragma unroll
    for (int jj = 0; jj < 2; ++jj) {
        int col = jbase + (w * 2 + jj) * 16 + l16;
        int cj = (w * 2 + jj) * 16 + l16;
        float bias = projb[col];
        float qmax = 0.f, qsum = 0.f, smax = 0.f, ssum = 0.f;
        #pragma unroll
        for (int rt = 0; rt < 8; ++rt) {
            #pragma unroll
            for (int r = 0; r < 4; ++r) {
                int row = rt * 16 + quad * 4 + r;
                float g1v = bf2f(g1[(size_t)(q_idx * 128 + row) * D_ + col]);
                float mix = s_p2mL[row] * s_pw2L[cj]
                          + s_p2mL[128 + row] * s_pw2L[128 + cj]
                          + s_p2mL[256 + row] * s_pw2L[256 + cj]
                          + s_p2mL[384 + row] * s_pw2L[384 + cj]
                          + s_p2mL[512 + row] * s_pw2L[512 + cj];
                float v = fmaxf(acc[rt][jj][r] + g1v + mix + bias, 0.f);
                qmax = fmaxf(qmax, v); qsum += v;
            }
        }
        #pragma unroll
        for (int r = 0; r < 4; ++r) {
            int t = quad * 4 + r;
            if (t < T_) {
                float g1v = bf2f(g1[(size_t)(5120 + bn * T_ + t) * D_ + col]);
                float s2v = bf2f(sw2[(size_t)(bq * T_ + t) * D_ + col]);
                float v = fmaxf(acc[8][jj][r] + g1v + s2v + bias, 0.f);
                smax = fmaxf(smax, v); ssum += v;
            }
        }
        qmax = fmaxf(qmax, __shfl_xor(qmax, 16, 64)); qmax = fmaxf(qmax, __shfl_xor(qmax, 32, 64));
        qsum += __shfl_xor(qsum, 16, 64);             qsum += __shfl_xor(qsum, 32, 64);
        smax = fmaxf(smax, __shfl_xor(smax, 16, 64)); smax = fmaxf(smax, __shfl_xor(smax, 32, 64));
        ssum += __shfl_xor(ssum, 16, 64);             ssum += __shfl_xor(ssum, 32, 64);
        if (quad == 0) {
            u16* cp = cat_ws + (size_t)bq * K4_;
            cp[col]           = f2bf(qmax);
            cp[D_ + col]      = f2bf(qsum * inv_qs);
            cp[2 * D_ + col]  = f2bf(smax);
            cp[3 * D_ + col]  = f2bf(ssum * 0.2f);
        }
    }
}

// ---------------- K5: relation MLP GEMM, split-K -> f32 partials ----------------
#define AST  40
__global__ __launch_bounds__(256) void k_relmlp(const u16* __restrict__ cat_ws,
                                                const u16* __restrict__ w1,
                                                float* __restrict__ part) {
    int mbase = blockIdx.y * 64;
    int jbase = blockIdx.x * 128;
    int ks = blockIdx.z;
    __shared__ __align__(16) u16 sA[64 * AST];
    __shared__ __align__(16) u16 sB[128 * AST];
    int tid = threadIdx.x;
    int lane = tid & 63, w = tid >> 6, quad = lane >> 4, l16 = lane & 15;
    f32x4 zero = {0.f, 0.f, 0.f, 0.f};
    f32x4 acc[4][2];
    #pragma unroll
    for (int rt = 0; rt < 4; ++rt) { acc[rt][0] = zero; acc[rt][1] = zero; }

    for (int kt = ks * 12; kt < ks * 12 + 12; ++kt) {
        int k0 = kt * 32;
        __syncthreads();
        {
            int row = tid >> 2, ko = (tid & 3) * 8;
            int grow = mbase + row;
            short8 val = short8{0, 0, 0, 0, 0, 0, 0, 0};
            if (grow < BQ_) val = *(const short8*)(cat_ws + (size_t)grow * K4_ + k0 + ko);
            *(short8*)(sA + row * AST + ko) = val;
        }
        for (int u = tid; u < 512; u += 256) {
            int row = u >> 2, ko = (u & 3) * 8;
            *(short8*)(sB + row * AST + ko) =
                *(const short8*)(w1 + (size_t)(jbase + row) * K4_ + k0 + ko);
        }
        __syncthreads();
        short8 af[4], bfr[2];
        #pragma unroll
        for (int rt = 0; rt < 4; ++rt)
            af[rt] = *(const short8*)(sA + (rt * 16 + l16) * AST + quad * 8);
        #pragma unroll
        for (int jj = 0; jj < 2; ++jj)
            bfr[jj] = *(const short8*)(sB + ((2 * w + jj) * 16 + l16) * AST + quad * 8);
        #pragma unroll
        for (int rt = 0; rt < 4; ++rt)
            #pragma unroll
            for (int jj = 0; jj < 2; ++jj)
                acc[rt][jj] = __builtin_amdgcn_mfma_f32_16x16x32_bf16(af[rt], bfr[jj], acc[rt][jj], 0, 0, 0);
    }
    #pragma unroll
    for (int jj = 0; jj < 2; ++jj) {
        int col = jbase + (2 * w + jj) * 16 + l16;
        #pragma unroll
        for (int rt = 0; rt < 4; ++rt) {
            #pragma unroll
            for (int r = 0; r < 4; ++r) {
                int grow = mbase + rt * 16 + quad * 4 + r;
                if (grow < BQ_)
                    part[((size_t)ks * BQ_ + grow) * D_ + col] = acc[rt][jj][r];
            }
        }
    }
}

// ---------------- K6: finish — sum partials, bias+relu, dot w2 ----------------
__global__ void k_rel_fin(const float* __restrict__ part, const float* __restrict__ b1,
                          const float* __restrict__ w2, const float* __restrict__ b2,
                          float* __restrict__ out) {
    int bq = blockIdx.x, tid = threadIdx.x;
    float a = 0.f;
    #pragma unroll
    for (int s = 0; s < 3; ++s) {
        int col = tid + s * 256;
        float sum = 0.f;
        #pragma unroll
        for (int ks = 0; ks < 8; ++ks) sum += part[((size_t)ks * BQ_ + bq) * D_ + col];
        float h = fmaxf(sum + b1[col], 0.f);
        a += h * w2[col];
    }
    __shared__ float red[256];
    red[tid] = a; __syncthreads();
    for (int off = 128; off >= 1; off >>= 1) {
        if (tid < off) red[tid] += red[tid + off];
        __syncthreads();
    }
    if (tid == 0) out[bq] = red[0] + b2[0];
}

extern "C" void kernel_launch(void* const* d_in, const int* in_sizes, int n_in,
                              void* d_out, int out_size, void* d_ws, size_t ws_size,
                              hipStream_t stream) {
    (void)in_sizes; (void)n_in; (void)out_size; (void)ws_size;
    const float* semb  = (const float*)d_in[0];
    const float* qemb  = (const float*)d_in[1];
    const float* smask = (const float*)d_in[2];
    const float* qmask = (const float*)d_in[3];
    const float* label = (const float*)d_in[4];
    const float* projw = (const float*)d_in[5];
    const float* projb = (const float*)d_in[6];
    const float* relw1 = (const float*)d_in[7];
    const float* relb1 = (const float*)d_in[8];
    const float* relw2 = (const float*)d_in[9];
    const float* relb2 = (const float*)d_in[10];

    char* ws = (char*)d_ws;
    u16*   A_all     = (u16*)  (ws + 0);           // 6400*768*2 = 9,830,400
    u16*   projw_bf  = (u16*)  (ws + 9830400);     // 4,718,592
    u16*   relw1_bf  = (u16*)  (ws + 14548992);    // 4,718,592
    float* proto_shot= (float*)(ws + 19267584);    // 768,000
    float* proto_f32 = (float*)(ws + 20035584);    // 153,600
    float* qssum     = (float*)(ws + 20189184);    // 896
    float* p2m_ws    = (float*)(ws + 20190080);    // 512,000
    u16*   pw2_ws    = (u16*)  (ws + 20702080);    // 76,800
    u16*   sw2_ws    = (u16*)  (ws + 20778880);    // 1,536,000
    u16*   cat_ws    = (u16*)  (ws + 22314880);    // 1,228,800
    u16*   g1_ws     = (u16*)  (ws + 23543680);    // 5248*768*2 = 8,060,928
    float* part_ws   = (float*)(ws + 31604608);    // 4,915,200
    u16*   qf_ws     = (u16*)  (ws + 36519808);    // 88,473,600
    // total 124,993,408 bytes

    k_convert3<<<2048, 256, 0, stream>>>(qemb, projw, relw1, A_all, projw_bf, relw1_bf);
    k_proto_shot<<<dim3(BNK_, 3), 256, 0, stream>>>(label, smask, semb, proto_shot);
    k_proto_mean<<<691, 256, 0, stream>>>(proto_shot, proto_f32, A_all);
    k_attn<<<BQ_, 256, 0, stream>>>(qemb, qmask, proto_f32, qf_ws, A_all + (size_t)R_SUP * D_,
                                    p2m_ws, qssum);
    k_gemm_gw<<<dim3(6, 50), 256, 0, stream>>>(A_all, projw_bf, g1_ws, sw2_ws, pw2_ws);
    k_gemm_q<<<1200, 256, 0, stream>>>(qf_ws, projw_bf, projb, g1_ws, pw2_ws, sw2_ws,
                                       p2m_ws, qssum, cat_ws);
    k_relmlp<<<dim3(6, 4, 8), 256, 0, stream>>>(cat_ws, relw1_bf, part_ws);
    k_rel_fin<<<BQ_, 256, 0, stream>>>(part_ws, relb1, relw2, relb2, (float*)d_out);
}

// Round 15
// 483.511 us; speedup vs baseline: 1.2539x; 1.2539x over previous
//
#include <hip/hip_runtime.h>

typedef unsigned short u16;
typedef __attribute__((ext_vector_type(8))) short short8;
typedef __attribute__((ext_vector_type(4))) float f32x4;

#define B_   2
#define N_   5
#define K_   5
#define Q_   4
#define T_   5
#define D_   768
#define L_   128
#define BN_  (B_*N_)            // 10
#define BNK_ (B_*N_*K_)         // 50
#define BQ_  (B_*N_*Q_*N_)      // 200
#define K4_  (4*D_)             // 3072
#define KFQ  1536               // fuse K in main GEMM (chunks 2,3 only)
#define AROWS 144               // 128 query + 5 es + 11 pad

#define QEMB_N  (40*128*768)    // 3,932,160
#define PROJW_N (768*3072)      // 2,359,296
// A_all row map: [0,5120) qemb | [5120,5170) proto | [5170,5248) zero
//                [5248,6248) sup | [6248,6298) proto | [6298,6400) zero
#define R_PROTO1 5120
#define R_SUP    5248
#define R_PROTO2 6248
#define R_TOTAL  6400

__device__ __forceinline__ float bf2f(u16 u) {
    return __uint_as_float(((unsigned)u) << 16);
}
__device__ __forceinline__ u16 f2bf(float f) {
    unsigned u = __float_as_uint(f);
    return (u16)((u + 0x7fffu + ((u >> 16) & 1u)) >> 16);
}
// async global->LDS, 16B per lane; lds base wave-uniform (HW adds lane*16)
__device__ __forceinline__ void gl_lds16(const u16* g, u16* l) {
    __builtin_amdgcn_global_load_lds(
        (const __attribute__((address_space(1))) unsigned int*)g,
        (__attribute__((address_space(3))) unsigned int*)l, 16, 0, 0);
}

// ---------------- K0: convert qemb (-> A_all rows 0..5119) / projw / relw1 ----------------
__global__ void k_convert3(const float* __restrict__ q, const float* __restrict__ pw,
                           const float* __restrict__ rw, u16* __restrict__ qo,
                           u16* __restrict__ po, u16* __restrict__ ro) {
    const long n1 = QEMB_N / 4, n2 = PROJW_N / 4;
    const long total = n1 + 2 * n2;
    for (long i = (long)blockIdx.x * 256 + threadIdx.x; i < total; i += (long)gridDim.x * 256) {
        const float* src; u16* dst; long k;
        if (i < n1)            { src = q;  dst = qo; k = i; }
        else if (i < n1 + n2)  { src = pw; dst = po; k = i - n1; }
        else                   { src = rw; dst = ro; k = i - n1 - n2; }
        float4 v = ((const float4*)src)[k];
        u16 o[4] = {f2bf(v.x), f2bf(v.y), f2bf(v.z), f2bf(v.w)};
        *(uint2*)(dst + k * 4) = *(const uint2*)o;
    }
}

// ---------------- K1: per-shot tag prototypes (segment-parallel) ----------------
__global__ void k_proto_shot(const float* __restrict__ label, const float* __restrict__ smask,
                             const float* __restrict__ semb, float* __restrict__ proto_shot) {
    int bnk = blockIdx.x;
    int s = blockIdx.y;                       // segment 0..2 (256 d's each)
    __shared__ int   s_tag[L_];
    __shared__ float s_w[L_];
    __shared__ float s_cnt[T_];
    int tid = threadIdx.x;
    if (tid < L_) {
        const float* lp = label + ((long)bnk * L_ + tid) * T_;
        float best = lp[0]; int bi = 0;
        #pragma unroll
        for (int t = 1; t < T_; ++t) { float v = lp[t]; if (v > best) { best = v; bi = t; } }
        s_tag[tid] = bi;
        s_w[tid]   = (bi == 0) ? smask[(long)bnk * L_ + tid] : 1.0f;
    }
    __syncthreads();
    if (tid < T_) {
        float c = 0.f;
        for (int l = 0; l < L_; ++l) if (s_tag[l] == tid) c += s_w[l];
        s_cnt[tid] = c;
    }
    __syncthreads();
    float acc[T_] = {};
    for (int l = 0; l < L_; ++l) {
        float w = s_w[l]; int tg = s_tag[l];
        float e = semb[((long)bnk * L_ + l) * D_ + tid + s * 256] * w;
        #pragma unroll
        for (int t = 0; t < T_; ++t) acc[t] += (tg == t) ? e : 0.0f;
    }
    int d = tid + s * 256;
    #pragma unroll
    for (int t = 0; t < T_; ++t) {
        float c = s_cnt[t];
        float v = (c > 0.f) ? acc[t] / fmaxf(c, 1.f) : 0.f;
        proto_shot[(bnk * T_ + t) * D_ + d] = v;
    }
}

// ---------------- K1b: mean over K shots -> proto_f32 + A_all proto rows + zero pads ----------------
__global__ void k_proto_mean(const float* __restrict__ proto_shot,
                             float* __restrict__ proto_f32, u16* __restrict__ A_all) {
    int bx = blockIdx.x;
    if (bx < 150) {
        int idx = bx * 256 + threadIdx.x;
        if (idx >= BN_ * T_ * D_) return;
        int r = idx / D_, d = idx - r * D_;
        int bn = r / T_;
        int rem = idx - bn * (T_ * D_);
        float s = 0.f;
        #pragma unroll
        for (int k = 0; k < K_; ++k) s += proto_shot[(bn * K_ + k) * (T_ * D_) + rem];
        s *= (1.f / K_);
        proto_f32[idx] = s;
        u16 b = f2bf(s);
        A_all[(size_t)(R_PROTO1 + r) * D_ + d] = b;
        A_all[(size_t)(R_PROTO2 + r) * D_ + d] = b;
    } else {
        // zero pad rows: [5170,5248) = 59904 elems, then [6298,6400) = 78336 elems
        int zidx = (bx - 150) * 256 + threadIdx.x;
        if (zidx >= 59904 + 78336) return;
        size_t off;
        if (zidx < 59904) off = (size_t)5170 * D_ + zidx;
        else              off = (size_t)6298 * D_ + (zidx - 59904);
        A_all[off] = 0;
    }
}

// ---------------- K2: co-attention -> es rows of qf, sup rows of A_all, p2m, qssum ----------------
__global__ void k_attn(const float* __restrict__ qemb, const float* __restrict__ qmask_g,
                       const float* __restrict__ proto_f32,
                       u16* __restrict__ qf, u16* __restrict__ supA,
                       float* __restrict__ p2m_ws, float* __restrict__ qssum_ws) {
    int x = blockIdx.x;
    int xcd = x & 7, slot = x >> 3;
    int g = (slot / 5) * 8 + xcd;           // q_idx 0..39
    int n2 = slot % 5;
    int bq = g * 5 + n2;
    int q_idx = g;
    int bn = (bq / (N_ * Q_ * N_)) * N_ + (bq % N_);
    __shared__ float s_proto[T_ * D_];
    __shared__ float s_att[T_][L_];
    __shared__ float s_ps[T_][L_];
    __shared__ float s_qm[L_];
    int tid = threadIdx.x;
    for (int i = tid; i < T_ * D_; i += 256) s_proto[i] = proto_f32[bn * T_ * D_ + i];
    if (tid < L_) s_qm[tid] = qmask_g[(long)q_idx * L_ + tid];
    __syncthreads();
    for (int p = tid; p < T_ * L_; p += 256) {
        int t = p >> 7, q = p & (L_ - 1);
        const float* pp = s_proto + t * D_;
        const float4* qp = (const float4*)(qemb + ((size_t)q_idx * L_ + q) * D_);
        float acc = 0.f;
        #pragma unroll 4
        for (int d = 0; d < D_ / 4; ++d) {
            float4 v = qp[d];
            acc += v.x * pp[4 * d] + v.y * pp[4 * d + 1] + v.z * pp[4 * d + 2] + v.w * pp[4 * d + 3];
        }
        s_att[t][q] = acc + 100.f * s_qm[q];
    }
    __syncthreads();
    if (tid < T_) {                       // softmax over q (support path)
        int t = tid; float m = -1e30f;
        for (int q = 0; q < L_; ++q) m = fmaxf(m, s_att[t][q]);
        float ss = 0.f;
        for (int q = 0; q < L_; ++q) { float e = __expf(s_att[t][q] - m); s_ps[t][q] = e; ss += e; }
        float inv = 1.f / ss;
        for (int q = 0; q < L_; ++q) s_ps[t][q] *= inv;
    } else if (tid >= 128) {              // softmax over t (query path) -> masked weights
        int q = tid - 128; float m = -1e30f;
        float e[T_];
        #pragma unroll
        for (int t = 0; t < T_; ++t) m = fmaxf(m, s_att[t][q]);
        float ss = 0.f;
        #pragma unroll
        for (int t = 0; t < T_; ++t) { e[t] = __expf(s_att[t][q] - m); ss += e[t]; }
        float inv = s_qm[q] / ss;
        #pragma unroll
        for (int t = 0; t < T_; ++t) p2m_ws[((size_t)bq * T_ + t) * L_ + q] = e[t] * inv;
    } else if (tid == 5) {
        float s = 0.f;
        for (int q = 0; q < L_; ++q) s += s_qm[q];
        qssum_ws[bq] = s;
    }
    __syncthreads();
    u16* qfb = qf + (size_t)bq * AROWS * KFQ;
    {   // support_[t] -> A_all sup rows (bf16) + es rows 128..132 of qf (chunks 2,3)
        float acc[T_][3] = {};
        #pragma unroll 4
        for (int q = 0; q < L_; ++q) {
            const float* qp = qemb + ((size_t)q_idx * L_ + q) * D_;
            float qv[3];
            #pragma unroll
            for (int s = 0; s < 3; ++s) qv[s] = qp[tid + s * 256];
            #pragma unroll
            for (int t = 0; t < T_; ++t) {
                float p = s_ps[t][q];
                #pragma unroll
                for (int s = 0; s < 3; ++s) acc[t][s] += p * qv[s];
            }
        }
        #pragma unroll
        for (int t = 0; t < T_; ++t) {
            u16* er = qfb + (size_t)(128 + t) * KFQ;
            #pragma unroll
            for (int s = 0; s < 3; ++s) {
                int d = tid + s * 256;
                float p = s_proto[t * D_ + d];
                float sv = acc[t][s];
                supA[((size_t)bq * T_ + t) * D_ + d] = f2bf(sv);
                er[d]       = f2bf(fabsf(p - sv));
                er[768 + d] = f2bf(p * sv);
            }
        }
    }
    {   // zero pad rows 133..143
        u16* pr2 = qfb + (size_t)133 * KFQ;
        short8 z = short8{0, 0, 0, 0, 0, 0, 0, 0};
        for (int i = tid; i < (11 * KFQ) / 8; i += 256) *(short8*)(pr2 + i * 8) = z;
    }
}

// ---------------- K2b: qf query rows (chunks 2,3) — 4x block parallelism over row-groups ----------------
__global__ void k_qf(const float* __restrict__ qemb, const float* __restrict__ proto_f32,
                     const float* __restrict__ p2m, u16* __restrict__ qf) {
    int bq = blockIdx.x;
    int rg = blockIdx.y;                     // row group 0..3 (32 rows each)
    int q_idx = bq / N_;
    int bn = (bq / (N_ * Q_ * N_)) * N_ + (bq % N_);
    __shared__ float s_proto[T_ * D_];
    __shared__ float s_p2[32][8];
    int tid = threadIdx.x;
    int w = tid >> 6, lane = tid & 63;
    for (int i = tid; i < T_ * D_; i += 256) s_proto[i] = proto_f32[bn * T_ * D_ + i];
    if (tid < 32 * T_) {
        int r = tid / T_, t = tid - r * T_;
        s_p2[r][t] = p2m[((size_t)bq * T_ + t) * L_ + rg * 32 + r];
    }
    __syncthreads();
    u16* qfb = qf + (size_t)bq * AROWS * KFQ;
    #pragma unroll
    for (int rr = 0; rr < 8; ++rr) {
        int rloc = w * 8 + rr;
        int row = rg * 32 + rloc;
        float p0 = s_p2[rloc][0], p1 = s_p2[rloc][1], p2v = s_p2[rloc][2];
        float p3 = s_p2[rloc][3], p4 = s_p2[rloc][4];
        const float* qrow = qemb + ((size_t)q_idx * L_ + row) * D_;
        u16* qr = qfb + (size_t)row * KFQ;
        #pragma unroll
        for (int ch = 0; ch < 12; ++ch) {
            int c = ch * 64 + lane;
            float m2 = p0 * s_proto[c] + p1 * s_proto[D_ + c] + p2v * s_proto[2 * D_ + c]
                     + p3 * s_proto[3 * D_ + c] + p4 * s_proto[4 * D_ + c];
            float qv = qrow[c];
            qr[c]       = f2bf(fabsf(qv - m2));
            qr[768 + c] = f2bf(qv * m2);
        }
    }
}

// ---------------- K3: combined G1+W2 GEMM: A_all(6400x768) @ projw(chunk0|chunk1)^T ----------------
#define SUBGW ((128 + 128) * 32)            // one 32-k sub-tile (A128+B128) in u16
__global__ __launch_bounds__(256) void k_gemm_gw(const u16* __restrict__ A_all,
                                                 const u16* __restrict__ projw_bf,
                                                 u16* __restrict__ g1, u16* __restrict__ sw2,
                                                 u16* __restrict__ pw2) {
    int mbase = blockIdx.y * 128;
    int jbase = blockIdx.x * 128;
    int boff = (mbase >= R_SUP) ? 768 : 0;
    __shared__ __align__(16) u16 sT[2][2 * SUBGW];
    int tid = threadIdx.x;
    int lane = tid & 63, w = tid >> 6, quad = lane >> 4, l16 = lane & 15;
    int srow = lane >> 2, sko = lane & 3;
    const u16* Ab = A_all + ((size_t)mbase + srow) * D_ + sko * 8;
    const u16* Bb = projw_bf + (size_t)(jbase + srow) * K4_ + boff + sko * 8;

    f32x4 zero = {0.f, 0.f, 0.f, 0.f};
    f32x4 acc[8][2];
    #pragma unroll
    for (int rt = 0; rt < 8; ++rt) { acc[rt][0] = zero; acc[rt][1] = zero; }

    auto issue = [&](int kt, int b) {
        #pragma unroll
        for (int s = 0; s < 2; ++s) {
            int k0 = kt * 64 + s * 32;
            u16* base = sT[b] + s * SUBGW;
            gl_lds16(Ab + (size_t)(w * 16) * D_ + k0, base + (w * 16) * 32);
            gl_lds16(Ab + (size_t)(64 + w * 16) * D_ + k0, base + (64 + w * 16) * 32);
            gl_lds16(Bb + (size_t)(w * 16) * K4_ + k0, base + (128 + w * 16) * 32);
            gl_lds16(Bb + (size_t)(64 + w * 16) * K4_ + k0, base + (128 + 64 + w * 16) * 32);
        }
    };

    issue(0, 0);
    for (int kt = 0; kt < D_ / 64; ++kt) {           // 12 iterations
        int cur = kt & 1;
        __syncthreads();
        if (kt + 1 < D_ / 64) issue(kt + 1, 1 - cur);
        #pragma unroll
        for (int s = 0; s < 2; ++s) {
            const u16* base = sT[cur] + s * SUBGW;
            short8 bfr[2];
            #pragma unroll
            for (int jj = 0; jj < 2; ++jj)
                bfr[jj] = *(const short8*)(base + (128 + (w * 2 + jj) * 16 + l16) * 32 + quad * 8);
            #pragma unroll
            for (int rt = 0; rt < 8; ++rt) {
                short8 a = *(const short8*)(base + (rt * 16 + l16) * 32 + quad * 8);
                acc[rt][0] = __builtin_amdgcn_mfma_f32_16x16x32_bf16(a, bfr[0], acc[rt][0], 0, 0, 0);
                acc[rt][1] = __builtin_amdgcn_mfma_f32_16x16x32_bf16(a, bfr[1], acc[rt][1], 0, 0, 0);
            }
        }
    }
    #pragma unroll
    for (int jj = 0; jj < 2; ++jj) {
        int col = jbase + (w * 2 + jj) * 16 + l16;
        #pragma unroll
        for (int rt = 0; rt < 8; ++rt)
            #pragma unroll
            for (int r = 0; r < 4; ++r) {
                int row = mbase + rt * 16 + quad * 4 + r;
                u16 v = f2bf(acc[rt][jj][r]);
                if (row < R_SUP)            g1[(size_t)row * D_ + col] = v;
                else if (row < R_PROTO2)    sw2[(size_t)(row - R_SUP) * D_ + col] = v;
                else if (row < R_PROTO2+50) pw2[(size_t)(row - R_PROTO2) * D_ + col] = v;
            }
    }
}

// ---------------- K4: main GEMM — j=128, BK=64, dbuf LDS (frozen best config) ----------------
#define SUBSZ ((AROWS + 128) * 32)          // one 32-k sub-tile (A+B) in u16
__global__ __launch_bounds__(256) void k_gemm_q(
        const u16* __restrict__ qf, const u16* __restrict__ projw_bf,
        const float* __restrict__ projb, const u16* __restrict__ g1,
        const u16* __restrict__ pw2, const u16* __restrict__ sw2,
        const float* __restrict__ p2m, const float* __restrict__ qssum_ws,
        u16* __restrict__ cat_ws) {
    int x = blockIdx.x;
    int xcd = x & 7, slot = x >> 3;          // slot 0..149
    int i = slot / 6, jslot = slot % 6;
    int g = (i / 5) * 8 + xcd;               // q-group 0..39, same map as k_attn
    int bq = g * 5 + (i % 5);
    int jbase = jslot * 128;
    int q_idx = bq / N_;
    int bn = (bq / (N_ * Q_ * N_)) * N_ + (bq % N_);
    __shared__ __align__(16) u16 sT[2][2 * SUBSZ];   // [buf][sub0|sub1]
    __shared__ float s_p2mL[T_ * 128];
    __shared__ float s_pw2L[T_ * 128];
    int tid = threadIdx.x;
    int lane = tid & 63, w = tid >> 6, quad = lane >> 4, l16 = lane & 15;
    int srow = lane >> 2, sko = lane & 3;
    const u16* Ab = qf + ((size_t)bq * AROWS + srow) * KFQ + sko * 8;
    const u16* Bb = projw_bf + (size_t)(jbase + srow) * K4_ + 1536 + sko * 8;

    f32x4 zero = {0.f, 0.f, 0.f, 0.f};
    f32x4 acc[9][2];
    #pragma unroll
    for (int rt = 0; rt < 9; ++rt) { acc[rt][0] = zero; acc[rt][1] = zero; }

    auto issue = [&](int kt, int b) {
        #pragma unroll
        for (int s = 0; s < 2; ++s) {
            int k0 = kt * 64 + s * 32;
            u16* base = sT[b] + s * SUBSZ;
            gl_lds16(Ab + (size_t)(w * 16) * KFQ + k0, base + (w * 16) * 32);
            gl_lds16(Ab + (size_t)(64 + w * 16) * KFQ + k0, base + (64 + w * 16) * 32);
            if (w == 0) gl_lds16(Ab + (size_t)128 * KFQ + k0, base + 128 * 32);
            gl_lds16(Bb + (size_t)(w * 16) * K4_ + k0, base + (AROWS + w * 16) * 32);
            gl_lds16(Bb + (size_t)(64 + w * 16) * K4_ + k0, base + (AROWS + 64 + w * 16) * 32);
        }
    };

    issue(0, 0);
    for (int kt = 0; kt < KFQ / 64; ++kt) {          // 24 iterations
        int cur = kt & 1;
        __syncthreads();
        if (kt + 1 < KFQ / 64) issue(kt + 1, 1 - cur);
        #pragma unroll
        for (int s = 0; s < 2; ++s) {
            const u16* base = sT[cur] + s * SUBSZ;
            short8 bfr[2];
            #pragma unroll
            for (int jj = 0; jj < 2; ++jj)
                bfr[jj] = *(const short8*)(base + (AROWS + (w * 2 + jj) * 16 + l16) * 32 + quad * 8);
            #pragma unroll
            for (int rt = 0; rt < 9; ++rt) {
                short8 a = *(const short8*)(base + (rt * 16 + l16) * 32 + quad * 8);
                acc[rt][0] = __builtin_amdgcn_mfma_f32_16x16x32_bf16(a, bfr[0], acc[rt][0], 0, 0, 0);
                acc[rt][1] = __builtin_amdgcn_mfma_f32_16x16x32_bf16(a, bfr[1], acc[rt][1], 0, 0, 0);
            }
        }
    }
    // epilogue staging: p2m + pw2 slices for this (bq, j) block
    for (int i2 = tid; i2 < T_ * 128; i2 += 256) {
        s_p2mL[i2] = p2m[(size_t)bq * (T_ * 128) + i2];
        s_pw2L[i2] = bf2f(pw2[(size_t)(bn * T_ + (i2 >> 7)) * D_ + jbase + (i2 & 127)]);
    }
    __syncthreads();
    float inv_qs = 1.f / qssum_ws[bq];
    #pragma unroll
    for (int jj = 0; jj < 2; ++jj) {
        int col = jbase + (w * 2 + jj) * 16 + l16;
        int cj = (w * 2 + jj) * 16 + l16;
        float bias = projb[col];
        float qmax = 0.f, qsum = 0.f, smax = 0.f, ssum = 0.f;
        #pragma unroll
        for (int rt = 0; rt < 8; ++rt) {
            #pragma unroll
            for (int r = 0; r < 4; ++r) {
                int row = rt * 16 + quad * 4 + r;
                float g1v = bf2f(g1[(size_t)(q_idx * 128 + row) * D_ + col]);
                float mix = s_p2mL[row] * s_pw2L[cj]
                          + s_p2mL[128 + row] * s_pw2L[128 + cj]
                          + s_p2mL[256 + row] * s_pw2L[256 + cj]
                          + s_p2mL[384 + row] * s_pw2L[384 + cj]
                          + s_p2mL[512 + row] * s_pw2L[512 + cj];
                float v = fmaxf(acc[rt][jj][r] + g1v + mix + bias, 0.f);
                qmax = fmaxf(qmax, v); qsum += v;
            }
        }
        #pragma unroll
        for (int r = 0; r < 4; ++r) {
            int t = quad * 4 + r;
            if (t < T_) {
                float g1v = bf2f(g1[(size_t)(5120 + bn * T_ + t) * D_ + col]);
                float s2v = bf2f(sw2[(size_t)(bq * T_ + t) * D_ + col]);
                float v = fmaxf(acc[8][jj][r] + g1v + s2v + bias, 0.f);
                smax = fmaxf(smax, v); ssum += v;
            }
        }
        qmax = fmaxf(qmax, __shfl_xor(qmax, 16, 64)); qmax = fmaxf(qmax, __shfl_xor(qmax, 32, 64));
        qsum += __shfl_xor(qsum, 16, 64);             qsum += __shfl_xor(qsum, 32, 64);
        smax = fmaxf(smax, __shfl_xor(smax, 16, 64)); smax = fmaxf(smax, __shfl_xor(smax, 32, 64));
        ssum += __shfl_xor(ssum, 16, 64);             ssum += __shfl_xor(ssum, 32, 64);
        if (quad == 0) {
            u16* cp = cat_ws + (size_t)bq * K4_;
            cp[col]           = f2bf(qmax);
            cp[D_ + col]      = f2bf(qsum * inv_qs);
            cp[2 * D_ + col]  = f2bf(smax);
            cp[3 * D_ + col]  = f2bf(ssum * 0.2f);
        }
    }
}

// ---------------- K5: relation MLP GEMM, split-K, dbuf gl_lds16 BK64 -> f32 partials ----------------
#define SUBRM ((64 + 128) * 32)             // one 32-k sub-tile (A64+B128) in u16
__global__ __launch_bounds__(256) void k_relmlp(const u16* __restrict__ cat_ws,
                                                const u16* __restrict__ w1,
                                                float* __restrict__ part) {
    int mbase = blockIdx.y * 64;
    int jbase = blockIdx.x * 128;
    int ks = blockIdx.z;                     // 8 k-splits of 384
    __shared__ __align__(16) u16 sT[2][2 * SUBRM];
    int tid = threadIdx.x;
    int lane = tid & 63, w = tid >> 6, quad = lane >> 4, l16 = lane & 15;
    int srow = lane >> 2, sko = lane & 3;
    const u16* Ab = cat_ws + (size_t)(mbase + srow) * K4_ + ks * 384 + sko * 8;  // rows >=200 read garbage, stores guarded
    const u16* Bb = w1 + (size_t)(jbase + srow) * K4_ + ks * 384 + sko * 8;

    f32x4 zero = {0.f, 0.f, 0.f, 0.f};
    f32x4 acc[4][2];
    #pragma unroll
    for (int rt = 0; rt < 4; ++rt) { acc[rt][0] = zero; acc[rt][1] = zero; }

    auto issue = [&](int kt, int b) {
        #pragma unroll
        for (int s = 0; s < 2; ++s) {
            int k0 = kt * 64 + s * 32;
            u16* base = sT[b] + s * SUBRM;
            gl_lds16(Ab + (size_t)(w * 16) * K4_ + k0, base + (w * 16) * 32);
            gl_lds16(Bb + (size_t)(w * 16) * K4_ + k0, base + (64 + w * 16) * 32);
            gl_lds16(Bb + (size_t)(64 + w * 16) * K4_ + k0, base + (64 + 64 + w * 16) * 32);
        }
    };

    issue(0, 0);
    for (int kt = 0; kt < 6; ++kt) {                 // 6 iterations of 64k = 384
        int cur = kt & 1;
        __syncthreads();
        if (kt + 1 < 6) issue(kt + 1, 1 - cur);
        #pragma unroll
        for (int s = 0; s < 2; ++s) {
            const u16* base = sT[cur] + s * SUBRM;
            short8 bfr[2];
            #pragma unroll
            for (int jj = 0; jj < 2; ++jj)
                bfr[jj] = *(const short8*)(base + (64 + (2 * w + jj) * 16 + l16) * 32 + quad * 8);
            #pragma unroll
            for (int rt = 0; rt < 4; ++rt) {
                short8 a = *(const short8*)(base + (rt * 16 + l16) * 32 + quad * 8);
                acc[rt][0] = __builtin_amdgcn_mfma_f32_16x16x32_bf16(a, bfr[0], acc[rt][0], 0, 0, 0);
                acc[rt][1] = __builtin_amdgcn_mfma_f32_16x16x32_bf16(a, bfr[1], acc[rt][1], 0, 0, 0);
            }
        }
    }
    #pragma unroll
    for (int jj = 0; jj < 2; ++jj) {
        int col = jbase + (2 * w + jj) * 16 + l16;
        #pragma unroll
        for (int rt = 0; rt < 4; ++rt) {
            #pragma unroll
            for (int r = 0; r < 4; ++r) {
                int grow = mbase + rt * 16 + quad * 4 + r;
                if (grow < BQ_)
                    part[((size_t)ks * BQ_ + grow) * D_ + col] = acc[rt][jj][r];
            }
        }
    }
}

// ---------------- K6: finish — sum partials, bias+relu, dot w2 ----------------
__global__ void k_rel_fin(const float* __restrict__ part, const float* __restrict__ b1,
                          const float* __restrict__ w2, const float* __restrict__ b2,
                          float* __restrict__ out) {
    int bq = blockIdx.x, tid = threadIdx.x;
    float a = 0.f;
    #pragma unroll
    for (int s = 0; s < 3; ++s) {
        int col = tid + s * 256;
        float sum = 0.f;
        #pragma unroll
        for (int ks = 0; ks < 8; ++ks) sum += part[((size_t)ks * BQ_ + bq) * D_ + col];
        float h = fmaxf(sum + b1[col], 0.f);
        a += h * w2[col];
    }
    __shared__ float red[256];
    red[tid] = a; __syncthreads();
    for (int off = 128; off >= 1; off >>= 1) {
        if (tid < off) red[tid] += red[tid + off];
        __syncthreads();
    }
    if (tid == 0) out[bq] = red[0] + b2[0];
}

extern "C" void kernel_launch(void* const* d_in, const int* in_sizes, int n_in,
                              void* d_out, int out_size, void* d_ws, size_t ws_size,
                              hipStream_t stream) {
    (void)in_sizes; (void)n_in; (void)out_size; (void)ws_size;
    const float* semb  = (const float*)d_in[0];
    const float* qemb  = (const float*)d_in[1];
    const float* smask = (const float*)d_in[2];
    const float* qmask = (const float*)d_in[3];
    const float* label = (const float*)d_in[4];
    const float* projw = (const float*)d_in[5];
    const float* projb = (const float*)d_in[6];
    const float* relw1 = (const float*)d_in[7];
    const float* relb1 = (const float*)d_in[8];
    const float* relw2 = (const float*)d_in[9];
    const float* relb2 = (const float*)d_in[10];

    char* ws = (char*)d_ws;
    u16*   A_all     = (u16*)  (ws + 0);           // 6400*768*2 = 9,830,400
    u16*   projw_bf  = (u16*)  (ws + 9830400);     // 4,718,592
    u16*   relw1_bf  = (u16*)  (ws + 14548992);    // 4,718,592
    float* proto_shot= (float*)(ws + 19267584);    // 768,000
    float* proto_f32 = (float*)(ws + 20035584);    // 153,600
    float* qssum     = (float*)(ws + 20189184);    // 896
    float* p2m_ws    = (float*)(ws + 20190080);    // 512,000
    u16*   pw2_ws    = (u16*)  (ws + 20702080);    // 76,800
    u16*   sw2_ws    = (u16*)  (ws + 20778880);    // 1,536,000
    u16*   cat_ws    = (u16*)  (ws + 22314880);    // 1,228,800
    u16*   g1_ws     = (u16*)  (ws + 23543680);    // 5248*768*2 = 8,060,928
    float* part_ws   = (float*)(ws + 31604608);    // 4,915,200
    u16*   qf_ws     = (u16*)  (ws + 36519808);    // 88,473,600
    // total 124,993,408 bytes

    k_convert3<<<2048, 256, 0, stream>>>(qemb, projw, relw1, A_all, projw_bf, relw1_bf);
    k_proto_shot<<<dim3(BNK_, 3), 256, 0, stream>>>(label, smask, semb, proto_shot);
    k_proto_mean<<<691, 256, 0, stream>>>(proto_shot, proto_f32, A_all);
    k_attn<<<BQ_, 256, 0, stream>>>(qemb, qmask, proto_f32, qf_ws, A_all + (size_t)R_SUP * D_,
                                    p2m_ws, qssum);
    k_qf<<<dim3(BQ_, 4), 256, 0, stream>>>(qemb, proto_f32, p2m_ws, qf_ws);
    k_gemm_gw<<<dim3(6, 50), 256, 0, stream>>>(A_all, projw_bf, g1_ws, sw2_ws, pw2_ws);
    k_gemm_q<<<1200, 256, 0, stream>>>(qf_ws, projw_bf, projb, g1_ws, pw2_ws, sw2_ws,
                                       p2m_ws, qssum, cat_ws);
    k_relmlp<<<dim3(6, 4, 8), 256, 0, stream>>>(cat_ws, relw1_bf, part_ws);
    k_rel_fin<<<BQ_, 256, 0, stream>>>(part_ws, relb1, relw2, relb2, (float*)d_out);
}

// Round 16
// 483.031 us; speedup vs baseline: 1.2551x; 1.0010x over previous
//
#include <hip/hip_runtime.h>

typedef unsigned short u16;
typedef __attribute__((ext_vector_type(8))) short short8;
typedef __attribute__((ext_vector_type(4))) float f32x4;

#define B_   2
#define N_   5
#define K_   5
#define Q_   4
#define T_   5
#define D_   768
#define L_   128
#define BN_  (B_*N_)            // 10
#define BNK_ (B_*N_*K_)         // 50
#define BQ_  (B_*N_*Q_*N_)      // 200
#define K4_  (4*D_)             // 3072
#define KFQ  1536               // fuse K in main GEMM (chunks 2,3 only)
#define AROWS 144               // 128 query + 5 es + 11 pad
#define NKT  48                 // k-tiles of 32 in KFQ

#define QEMB_N  (40*128*768)    // 3,932,160
#define PROJW_N (768*3072)      // 2,359,296
// A_all row map: [0,5120) qemb | [5120,5170) proto | [5170,5248) zero
//                [5248,6248) sup | [6248,6298) proto | [6298,6400) zero
#define R_PROTO1 5120
#define R_SUP    5248
#define R_PROTO2 6248

__device__ __forceinline__ float bf2f(u16 u) {
    return __uint_as_float(((unsigned)u) << 16);
}
__device__ __forceinline__ u16 f2bf(float f) {
    unsigned u = __float_as_uint(f);
    return (u16)((u + 0x7fffu + ((u >> 16) & 1u)) >> 16);
}
// async global->LDS, 16B per lane; lds base wave-uniform (HW adds lane*16)
__device__ __forceinline__ void gl_lds16(const u16* g, u16* l) {
    __builtin_amdgcn_global_load_lds(
        (const __attribute__((address_space(1))) unsigned int*)g,
        (__attribute__((address_space(3))) unsigned int*)l, 16, 0, 0);
}

// ---------------- K0: convert qemb (-> A_all rows 0..5119) / projw / relw1 ----------------
__global__ void k_convert3(const float* __restrict__ q, const float* __restrict__ pw,
                           const float* __restrict__ rw, u16* __restrict__ qo,
                           u16* __restrict__ po, u16* __restrict__ ro) {
    const long n1 = QEMB_N / 4, n2 = PROJW_N / 4;
    const long total = n1 + 2 * n2;
    for (long i = (long)blockIdx.x * 256 + threadIdx.x; i < total; i += (long)gridDim.x * 256) {
        const float* src; u16* dst; long k;
        if (i < n1)            { src = q;  dst = qo; k = i; }
        else if (i < n1 + n2)  { src = pw; dst = po; k = i - n1; }
        else                   { src = rw; dst = ro; k = i - n1 - n2; }
        float4 v = ((const float4*)src)[k];
        u16 o[4] = {f2bf(v.x), f2bf(v.y), f2bf(v.z), f2bf(v.w)};
        *(uint2*)(dst + k * 4) = *(const uint2*)o;
    }
}

// ---------------- K0b: tile projw chunks 2,3 into MFMA-fragment layout ----------------
// pwt[(jt*48 + kt)*512 + n*32 + q*8 + i] = projw[jt*16+n][1536 + kt*32 + q*8 + i]
__global__ void k_tileB(const float* __restrict__ pw, u16* __restrict__ pwt) {
    int tidx = blockIdx.x * 4 + (threadIdx.x >> 6);   // tile 0..2303
    int lane = threadIdx.x & 63, n = lane & 15, quad = lane >> 4;
    int jt = tidx / NKT, kt = tidx - jt * NKT;
    const float* src = pw + (size_t)(jt * 16 + n) * K4_ + 1536 + kt * 32 + quad * 8;
    float4 v0 = *(const float4*)src, v1 = *(const float4*)(src + 4);
    float qv[8] = {v0.x, v0.y, v0.z, v0.w, v1.x, v1.y, v1.z, v1.w};
    short8 o;
    #pragma unroll
    for (int i = 0; i < 8; ++i) o[i] = (short)f2bf(qv[i]);
    *(short8*)(pwt + (size_t)tidx * 512 + n * 32 + quad * 8) = o;
}

// ---------------- K1: per-shot tag prototypes (segment-parallel) ----------------
__global__ void k_proto_shot(const float* __restrict__ label, const float* __restrict__ smask,
                             const float* __restrict__ semb, float* __restrict__ proto_shot) {
    int bnk = blockIdx.x;
    int s = blockIdx.y;                       // segment 0..2 (256 d's each)
    __shared__ int   s_tag[L_];
    __shared__ float s_w[L_];
    __shared__ float s_cnt[T_];
    int tid = threadIdx.x;
    if (tid < L_) {
        const float* lp = label + ((long)bnk * L_ + tid) * T_;
        float best = lp[0]; int bi = 0;
        #pragma unroll
        for (int t = 1; t < T_; ++t) { float v = lp[t]; if (v > best) { best = v; bi = t; } }
        s_tag[tid] = bi;
        s_w[tid]   = (bi == 0) ? smask[(long)bnk * L_ + tid] : 1.0f;
    }
    __syncthreads();
    if (tid < T_) {
        float c = 0.f;
        for (int l = 0; l < L_; ++l) if (s_tag[l] == tid) c += s_w[l];
        s_cnt[tid] = c;
    }
    __syncthreads();
    float acc[T_] = {};
    for (int l = 0; l < L_; ++l) {
        float w = s_w[l]; int tg = s_tag[l];
        float e = semb[((long)bnk * L_ + l) * D_ + tid + s * 256] * w;
        #pragma unroll
        for (int t = 0; t < T_; ++t) acc[t] += (tg == t) ? e : 0.0f;
    }
    int d = tid + s * 256;
    #pragma unroll
    for (int t = 0; t < T_; ++t) {
        float c = s_cnt[t];
        float v = (c > 0.f) ? acc[t] / fmaxf(c, 1.f) : 0.f;
        proto_shot[(bnk * T_ + t) * D_ + d] = v;
    }
}

// ---------------- K1b: mean over K shots -> proto_f32 + A_all proto rows + zero pads ----------------
__global__ void k_proto_mean(const float* __restrict__ proto_shot,
                             float* __restrict__ proto_f32, u16* __restrict__ A_all) {
    int bx = blockIdx.x;
    if (bx < 150) {
        int idx = bx * 256 + threadIdx.x;
        if (idx >= BN_ * T_ * D_) return;
        int r = idx / D_, d = idx - r * D_;
        int bn = r / T_;
        int rem = idx - bn * (T_ * D_);
        float s = 0.f;
        #pragma unroll
        for (int k = 0; k < K_; ++k) s += proto_shot[(bn * K_ + k) * (T_ * D_) + rem];
        s *= (1.f / K_);
        proto_f32[idx] = s;
        u16 b = f2bf(s);
        A_all[(size_t)(R_PROTO1 + r) * D_ + d] = b;
        A_all[(size_t)(R_PROTO2 + r) * D_ + d] = b;
    } else {
        int zidx = (bx - 150) * 256 + threadIdx.x;
        if (zidx >= 59904 + 78336) return;
        size_t off;
        if (zidx < 59904) off = (size_t)5170 * D_ + zidx;
        else              off = (size_t)6298 * D_ + (zidx - 59904);
        A_all[off] = 0;
    }
}

// ---------------- K2: co-attention -> es tiles of qft, sup rows of A_all, p2m, qssum ----------------
__global__ void k_attn(const float* __restrict__ qemb, const float* __restrict__ qmask_g,
                       const float* __restrict__ proto_f32,
                       u16* __restrict__ qft, u16* __restrict__ supA,
                       float* __restrict__ p2m_ws, float* __restrict__ qssum_ws) {
    int x = blockIdx.x;
    int xcd = x & 7, slot = x >> 3;
    int g = (slot / 5) * 8 + xcd;           // q_idx 0..39
    int n2 = slot % 5;
    int bq = g * 5 + n2;
    int q_idx = g;
    int bn = (bq / (N_ * Q_ * N_)) * N_ + (bq % N_);
    __shared__ float s_proto[T_ * D_];
    __shared__ float s_att[T_][L_];
    __shared__ float s_ps[T_][L_];
    __shared__ float s_qm[L_];
    int tid = threadIdx.x;
    for (int i = tid; i < T_ * D_; i += 256) s_proto[i] = proto_f32[bn * T_ * D_ + i];
    if (tid < L_) s_qm[tid] = qmask_g[(long)q_idx * L_ + tid];
    __syncthreads();
    for (int p = tid; p < T_ * L_; p += 256) {
        int t = p >> 7, q = p & (L_ - 1);
        const float* pp = s_proto + t * D_;
        const float4* qp = (const float4*)(qemb + ((size_t)q_idx * L_ + q) * D_);
        float acc = 0.f;
        #pragma unroll 4
        for (int d = 0; d < D_ / 4; ++d) {
            float4 v = qp[d];
            acc += v.x * pp[4 * d] + v.y * pp[4 * d + 1] + v.z * pp[4 * d + 2] + v.w * pp[4 * d + 3];
        }
        s_att[t][q] = acc + 100.f * s_qm[q];
    }
    __syncthreads();
    if (tid < T_) {                       // softmax over q (support path)
        int t = tid; float m = -1e30f;
        for (int q = 0; q < L_; ++q) m = fmaxf(m, s_att[t][q]);
        float ss = 0.f;
        for (int q = 0; q < L_; ++q) { float e = __expf(s_att[t][q] - m); s_ps[t][q] = e; ss += e; }
        float inv = 1.f / ss;
        for (int q = 0; q < L_; ++q) s_ps[t][q] *= inv;
    } else if (tid >= 128) {              // softmax over t (query path) -> masked weights
        int q = tid - 128; float m = -1e30f;
        float e[T_];
        #pragma unroll
        for (int t = 0; t < T_; ++t) m = fmaxf(m, s_att[t][q]);
        float ss = 0.f;
        #pragma unroll
        for (int t = 0; t < T_; ++t) { e[t] = __expf(s_att[t][q] - m); ss += e[t]; }
        float inv = s_qm[q] / ss;
        #pragma unroll
        for (int t = 0; t < T_; ++t) p2m_ws[((size_t)bq * T_ + t) * L_ + q] = e[t] * inv;
    } else if (tid == 5) {
        float s = 0.f;
        for (int q = 0; q < L_; ++q) s += s_qm[q];
        qssum_ws[bq] = s;
    }
    __syncthreads();
    u16* et = qft + ((size_t)(bq * 9 + 8) * NKT) * 512;   // es tile group (rt=8)
    {   // support_[t] -> A_all sup rows (bf16) + es tiles (chunks 2,3) of qft
        float acc[T_][3] = {};
        #pragma unroll 4
        for (int q = 0; q < L_; ++q) {
            const float* qp = qemb + ((size_t)q_idx * L_ + q) * D_;
            float qv[3];
            #pragma unroll
            for (int s = 0; s < 3; ++s) qv[s] = qp[tid + s * 256];
            #pragma unroll
            for (int t = 0; t < T_; ++t) {
                float p = s_ps[t][q];
                #pragma unroll
                for (int s = 0; s < 3; ++s) acc[t][s] += p * qv[s];
            }
        }
        #pragma unroll
        for (int t = 0; t < T_; ++t) {
            #pragma unroll
            for (int s = 0; s < 3; ++s) {
                int d = tid + s * 256;
                float p = s_proto[t * D_ + d];
                float sv = acc[t][s];
                supA[((size_t)bq * T_ + t) * D_ + d] = f2bf(sv);
                int kt = d >> 5, c = d & 31;
                et[(size_t)kt * 512 + t * 32 + c]        = f2bf(fabsf(p - sv));
                et[(size_t)(24 + kt) * 512 + t * 32 + c] = f2bf(p * sv);
            }
        }
    }
    {   // zero pad rows 5..15 of every es tile (48 kt x 11 rows x 32)
        for (int i = tid; i < NKT * 11 * 32; i += 256) {
            int kt = i / 352, rem = i - kt * 352;
            int r = 5 + (rem >> 5), c = rem & 31;
            et[(size_t)kt * 512 + r * 32 + c] = 0;
        }
    }
}

// ---------------- K2b: qf query tiles (chunks 2,3) in fragment layout ----------------
// grid (200 bq, 8 rt). Wave handles one (rt, kt) tile per step; writes dense 1KB.
__global__ void k_qf(const float* __restrict__ qemb, const float* __restrict__ proto_f32,
                     const float* __restrict__ p2m, u16* __restrict__ qft) {
    int bq = blockIdx.x;
    int rt = blockIdx.y;                     // row-tile 0..7
    int q_idx = bq / N_;
    int bn = (bq / (N_ * Q_ * N_)) * N_ + (bq % N_);
    __shared__ float s_proto[T_ * D_];
    __shared__ float s_p2[16][8];
    int tid = threadIdx.x;
    int w = tid >> 6, lane = tid & 63, r = lane & 15, quad = lane >> 4;
    for (int i = tid; i < T_ * D_; i += 256) s_proto[i] = proto_f32[bn * T_ * D_ + i];
    if (tid < 16 * T_) {
        int rr = tid / T_, t = tid - rr * T_;
        s_p2[rr][t] = p2m[((size_t)bq * T_ + t) * L_ + rt * 16 + rr];
    }
    __syncthreads();
    int row = rt * 16 + r;
    float p0 = s_p2[r][0], p1 = s_p2[r][1], p2v = s_p2[r][2], p3 = s_p2[r][3], p4 = s_p2[r][4];
    const float* qrow = qemb + ((size_t)q_idx * L_ + row) * D_;
    u16* qtb = qft + ((size_t)(bq * 9 + rt) * NKT) * 512 + r * 32 + quad * 8;
    for (int kt = w; kt < NKT; kt += 4) {
        int dbase = ((kt < 24) ? kt : kt - 24) * 32 + quad * 8;
        float4 v0 = *(const float4*)(qrow + dbase);
        float4 v1 = *(const float4*)(qrow + dbase + 4);
        float qv[8] = {v0.x, v0.y, v0.z, v0.w, v1.x, v1.y, v1.z, v1.w};
        short8 o;
        #pragma unroll
        for (int i = 0; i < 8; ++i) {
            int d = dbase + i;
            float m2 = p0 * s_proto[d] + p1 * s_proto[D_ + d] + p2v * s_proto[2 * D_ + d]
                     + p3 * s_proto[3 * D_ + d] + p4 * s_proto[4 * D_ + d];
            float v = (kt < 24) ? fabsf(qv[i] - m2) : qv[i] * m2;
            o[i] = (short)f2bf(v);
        }
        *(short8*)(qtb + (size_t)kt * 512) = o;
    }
}

// ---------------- K3: combined G1+W2 GEMM: A_all(6400x768) @ projw(chunk0|chunk1)^T ----------------
#define SUBGW ((128 + 128) * 32)            // one 32-k sub-tile (A128+B128) in u16
__global__ __launch_bounds__(256) void k_gemm_gw(const u16* __restrict__ A_all,
                                                 const u16* __restrict__ projw_bf,
                                                 u16* __restrict__ g1, u16* __restrict__ sw2,
                                                 u16* __restrict__ pw2) {
    int mbase = blockIdx.y * 128;
    int jbase = blockIdx.x * 128;
    int boff = (mbase >= R_SUP) ? 768 : 0;
    __shared__ __align__(16) u16 sT[2][2 * SUBGW];
    int tid = threadIdx.x;
    int lane = tid & 63, w = tid >> 6, quad = lane >> 4, l16 = lane & 15;
    int srow = lane >> 2, sko = lane & 3;
    const u16* Ab = A_all + ((size_t)mbase + srow) * D_ + sko * 8;
    const u16* Bb = projw_bf + (size_t)(jbase + srow) * K4_ + boff + sko * 8;

    f32x4 zero = {0.f, 0.f, 0.f, 0.f};
    f32x4 acc[8][2];
    #pragma unroll
    for (int rt = 0; rt < 8; ++rt) { acc[rt][0] = zero; acc[rt][1] = zero; }

    auto issue = [&](int kt, int b) {
        #pragma unroll
        for (int s = 0; s < 2; ++s) {
            int k0 = kt * 64 + s * 32;
            u16* base = sT[b] + s * SUBGW;
            gl_lds16(Ab + (size_t)(w * 16) * D_ + k0, base + (w * 16) * 32);
            gl_lds16(Ab + (size_t)(64 + w * 16) * D_ + k0, base + (64 + w * 16) * 32);
            gl_lds16(Bb + (size_t)(w * 16) * K4_ + k0, base + (128 + w * 16) * 32);
            gl_lds16(Bb + (size_t)(64 + w * 16) * K4_ + k0, base + (128 + 64 + w * 16) * 32);
        }
    };

    issue(0, 0);
    for (int kt = 0; kt < D_ / 64; ++kt) {           // 12 iterations
        int cur = kt & 1;
        __syncthreads();
        if (kt + 1 < D_ / 64) issue(kt + 1, 1 - cur);
        #pragma unroll
        for (int s = 0; s < 2; ++s) {
            const u16* base = sT[cur] + s * SUBGW;
            short8 bfr[2];
            #pragma unroll
            for (int jj = 0; jj < 2; ++jj)
                bfr[jj] = *(const short8*)(base + (128 + (w * 2 + jj) * 16 + l16) * 32 + quad * 8);
            #pragma unroll
            for (int rt = 0; rt < 8; ++rt) {
                short8 a = *(const short8*)(base + (rt * 16 + l16) * 32 + quad * 8);
                acc[rt][0] = __builtin_amdgcn_mfma_f32_16x16x32_bf16(a, bfr[0], acc[rt][0], 0, 0, 0);
                acc[rt][1] = __builtin_amdgcn_mfma_f32_16x16x32_bf16(a, bfr[1], acc[rt][1], 0, 0, 0);
            }
        }
    }
    #pragma unroll
    for (int jj = 0; jj < 2; ++jj) {
        int col = jbase + (w * 2 + jj) * 16 + l16;
        #pragma unroll
        for (int rt = 0; rt < 8; ++rt)
            #pragma unroll
            for (int r = 0; r < 4; ++r) {
                int row = mbase + rt * 16 + quad * 4 + r;
                u16 v = f2bf(acc[rt][jj][r]);
                if (row < R_SUP)            g1[(size_t)row * D_ + col] = v;
                else if (row < R_PROTO2)    sw2[(size_t)(row - R_SUP) * D_ + col] = v;
                else if (row < R_PROTO2+50) pw2[(size_t)(row - R_PROTO2) * D_ + col] = v;
            }
    }
}

// ---------------- K4: main GEMM — barrier-free register pipeline over tiled fragments ----------------
// grid 1200 swizzled. Each fragment load = one dense, fully-coalesced 1KB global_load_dwordx4.
__global__ __launch_bounds__(256) void k_gemm_q(
        const u16* __restrict__ qft, const u16* __restrict__ pwt,
        const float* __restrict__ projb, const u16* __restrict__ g1,
        const u16* __restrict__ pw2, const u16* __restrict__ sw2,
        const float* __restrict__ p2m, const float* __restrict__ qssum_ws,
        u16* __restrict__ cat_ws) {
    int x = blockIdx.x;
    int xcd = x & 7, slot = x >> 3;          // slot 0..149
    int i = slot / 6, jslot = slot % 6;
    int g = (i / 5) * 8 + xcd;               // q-group 0..39, same map as k_attn
    int bq = g * 5 + (i % 5);
    int jbase = jslot * 128;
    int q_idx = bq / N_;
    int bn = (bq / (N_ * Q_ * N_)) * N_ + (bq % N_);
    __shared__ float s_p2mL[T_ * 128];
    __shared__ float s_pw2L[T_ * 128];
    int tid = threadIdx.x;
    int lane = tid & 63, w = tid >> 6, quad = lane >> 4, l16 = lane & 15;
    int loff = l16 * 32 + quad * 8;          // fragment lane offset within a 16x32 tile

    const u16* Ab = qft + (size_t)bq * 9 * NKT * 512 + loff;
    const u16* Bb = pwt + (size_t)(jslot * 8 + w * 2) * NKT * 512 + loff;

    f32x4 zero = {0.f, 0.f, 0.f, 0.f};
    f32x4 acc[9][2];
    #pragma unroll
    for (int rt = 0; rt < 9; ++rt) { acc[rt][0] = zero; acc[rt][1] = zero; }

    short8 a0[9], b0[2], a1[9], b1[2];
    auto loadf = [&](short8* A, short8* Bf, int kt) {
        #pragma unroll
        for (int rt = 0; rt < 9; ++rt)
            A[rt] = *(const short8*)(Ab + (size_t)(rt * NKT + kt) * 512);
        #pragma unroll
        for (int jj = 0; jj < 2; ++jj)
            Bf[jj] = *(const short8*)(Bb + (size_t)(jj * NKT + kt) * 512);
    };
    auto domfma = [&](short8* A, short8* Bf) {
        #pragma unroll
        for (int rt = 0; rt < 9; ++rt) {
            acc[rt][0] = __builtin_amdgcn_mfma_f32_16x16x32_bf16(A[rt], Bf[0], acc[rt][0], 0, 0, 0);
            acc[rt][1] = __builtin_amdgcn_mfma_f32_16x16x32_bf16(A[rt], Bf[1], acc[rt][1], 0, 0, 0);
        }
    };

    loadf(a0, b0, 0);
    for (int kt = 0; kt < NKT; kt += 2) {
        loadf(a1, b1, kt + 1);
        domfma(a0, b0);
        if (kt + 2 < NKT) loadf(a0, b0, kt + 2);
        domfma(a1, b1);
    }
    // epilogue staging: p2m + pw2 slices for this (bq, j) block
    for (int i2 = tid; i2 < T_ * 128; i2 += 256) {
        s_p2mL[i2] = p2m[(size_t)bq * (T_ * 128) + i2];
        s_pw2L[i2] = bf2f(pw2[(size_t)(bn * T_ + (i2 >> 7)) * D_ + jbase + (i2 & 127)]);
    }
    __syncthreads();
    float inv_qs = 1.f / qssum_ws[bq];
    #pragma unroll
    for (int jj = 0; jj < 2; ++jj) {
        int col = jbase + (w * 2 + jj) * 16 + l16;
        int cj = (w * 2 + jj) * 16 + l16;
        float bias = projb[col];
        float qmax = 0.f, qsum = 0.f, smax = 0.f, ssum = 0.f;
        #pragma unroll
        for (int rt = 0; rt < 8; ++rt) {
            #pragma unroll
            for (int r = 0; r < 4; ++r) {
                int row = rt * 16 + quad * 4 + r;
                float g1v = bf2f(g1[(size_t)(q_idx * 128 + row) * D_ + col]);
                float mix = s_p2mL[row] * s_pw2L[cj]
                          + s_p2mL[128 + row] * s_pw2L[128 + cj]
                          + s_p2mL[256 + row] * s_pw2L[256 + cj]
                          + s_p2mL[384 + row] * s_pw2L[384 + cj]
                          + s_p2mL[512 + row] * s_pw2L[512 + cj];
                float v = fmaxf(acc[rt][jj][r] + g1v + mix + bias, 0.f);
                qmax = fmaxf(qmax, v); qsum += v;
            }
        }
        #pragma unroll
        for (int r = 0; r < 4; ++r) {
            int t = quad * 4 + r;
            if (t < T_) {
                float g1v = bf2f(g1[(size_t)(5120 + bn * T_ + t) * D_ + col]);
                float s2v = bf2f(sw2[(size_t)(bq * T_ + t) * D_ + col]);
                float v = fmaxf(acc[8][jj][r] + g1v + s2v + bias, 0.f);
                smax = fmaxf(smax, v); ssum += v;
            }
        }
        qmax = fmaxf(qmax, __shfl_xor(qmax, 16, 64)); qmax = fmaxf(qmax, __shfl_xor(qmax, 32, 64));
        qsum += __shfl_xor(qsum, 16, 64);             qsum += __shfl_xor(qsum, 32, 64);
        smax = fmaxf(smax, __shfl_xor(smax, 16, 64)); smax = fmaxf(smax, __shfl_xor(smax, 32, 64));
        ssum += __shfl_xor(ssum, 16, 64);             ssum += __shfl_xor(ssum, 32, 64);
        if (quad == 0) {
            u16* cp = cat_ws + (size_t)bq * K4_;
            cp[col]           = f2bf(qmax);
            cp[D_ + col]      = f2bf(qsum * inv_qs);
            cp[2 * D_ + col]  = f2bf(smax);
            cp[3 * D_ + col]  = f2bf(ssum * 0.2f);
        }
    }
}

// ---------------- K5: relation MLP GEMM, split-K, dbuf gl_lds16 BK64 -> f32 partials ----------------
#define SUBRM ((64 + 128) * 32)             // one 32-k sub-tile (A64+B128) in u16
__global__ __launch_bounds__(256) void k_relmlp(const u16* __restrict__ cat_ws,
                                                const u16* __restrict__ w1,
                                                float* __restrict__ part) {
    int mbase = blockIdx.y * 64;
    int jbase = blockIdx.x * 128;
    int ks = blockIdx.z;                     // 8 k-splits of 384
    __shared__ __align__(16) u16 sT[2][2 * SUBRM];
    int tid = threadIdx.x;
    int lane = tid & 63, w = tid >> 6, quad = lane >> 4, l16 = lane & 15;
    int srow = lane >> 2, sko = lane & 3;
    const u16* Ab = cat_ws + (size_t)(mbase + srow) * K4_ + ks * 384 + sko * 8;
    const u16* Bb = w1 + (size_t)(jbase + srow) * K4_ + ks * 384 + sko * 8;

    f32x4 zero = {0.f, 0.f, 0.f, 0.f};
    f32x4 acc[4][2];
    #pragma unroll
    for (int rt = 0; rt < 4; ++rt) { acc[rt][0] = zero; acc[rt][1] = zero; }

    auto issue = [&](int kt, int b) {
        #pragma unroll
        for (int s = 0; s < 2; ++s) {
            int k0 = kt * 64 + s * 32;
            u16* base = sT[b] + s * SUBRM;
            gl_lds16(Ab + (size_t)(w * 16) * K4_ + k0, base + (w * 16) * 32);
            gl_lds16(Bb + (size_t)(w * 16) * K4_ + k0, base + (64 + w * 16) * 32);
            gl_lds16(Bb + (size_t)(64 + w * 16) * K4_ + k0, base + (64 + 64 + w * 16) * 32);
        }
    };

    issue(0, 0);
    for (int kt = 0; kt < 6; ++kt) {                 // 6 iterations of 64k = 384
        int cur = kt & 1;
        __syncthreads();
        if (kt + 1 < 6) issue(kt + 1, 1 - cur);
        #pragma unroll
        for (int s = 0; s < 2; ++s) {
            const u16* base = sT[cur] + s * SUBRM;
            short8 bfr[2];
            #pragma unroll
            for (int jj = 0; jj < 2; ++jj)
                bfr[jj] = *(const short8*)(base + (64 + (2 * w + jj) * 16 + l16) * 32 + quad * 8);
            #pragma unroll
            for (int rt = 0; rt < 4; ++rt) {
                short8 a = *(const short8*)(base + (rt * 16 + l16) * 32 + quad * 8);
                acc[rt][0] = __builtin_amdgcn_mfma_f32_16x16x32_bf16(a, bfr[0], acc[rt][0], 0, 0, 0);
                acc[rt][1] = __builtin_amdgcn_mfma_f32_16x16x32_bf16(a, bfr[1], acc[rt][1], 0, 0, 0);
            }
        }
    }
    #pragma unroll
    for (int jj = 0; jj < 2; ++jj) {
        int col = jbase + (2 * w + jj) * 16 + l16;
        #pragma unroll
        for (int rt = 0; rt < 4; ++rt) {
            #pragma unroll
            for (int r = 0; r < 4; ++r) {
                int grow = mbase + rt * 16 + quad * 4 + r;
                if (grow < BQ_)
                    part[((size_t)ks * BQ_ + grow) * D_ + col] = acc[rt][jj][r];
            }
        }
    }
}

// ---------------- K6: finish — sum partials, bias+relu, dot w2 ----------------
__global__ void k_rel_fin(const float* __restrict__ part, const float* __restrict__ b1,
                          const float* __restrict__ w2, const float* __restrict__ b2,
                          float* __restrict__ out) {
    int bq = blockIdx.x, tid = threadIdx.x;
    float a = 0.f;
    #pragma unroll
    for (int s = 0; s < 3; ++s) {
        int col = tid + s * 256;
        float sum = 0.f;
        #pragma unroll
        for (int ks = 0; ks < 8; ++ks) sum += part[((size_t)ks * BQ_ + bq) * D_ + col];
        float h = fmaxf(sum + b1[col], 0.f);
        a += h * w2[col];
    }
    __shared__ float red[256];
    red[tid] = a; __syncthreads();
    for (int off = 128; off >= 1; off >>= 1) {
        if (tid < off) red[tid] += red[tid + off];
        __syncthreads();
    }
    if (tid == 0) out[bq] = red[0] + b2[0];
}

extern "C" void kernel_launch(void* const* d_in, const int* in_sizes, int n_in,
                              void* d_out, int out_size, void* d_ws, size_t ws_size,
                              hipStream_t stream) {
    (void)in_sizes; (void)n_in; (void)out_size; (void)ws_size;
    const float* semb  = (const float*)d_in[0];
    const float* qemb  = (const float*)d_in[1];
    const float* smask = (const float*)d_in[2];
    const float* qmask = (const float*)d_in[3];
    const float* label = (const float*)d_in[4];
    const float* projw = (const float*)d_in[5];
    const float* projb = (const float*)d_in[6];
    const float* relw1 = (const float*)d_in[7];
    const float* relb1 = (const float*)d_in[8];
    const float* relw2 = (const float*)d_in[9];
    const float* relb2 = (const float*)d_in[10];

    char* ws = (char*)d_ws;
    u16*   A_all     = (u16*)  (ws + 0);           // 9,830,400
    u16*   projw_bf  = (u16*)  (ws + 9830400);     // 4,718,592
    u16*   relw1_bf  = (u16*)  (ws + 14548992);    // 4,718,592
    float* proto_shot= (float*)(ws + 19267584);    // 768,000
    float* proto_f32 = (float*)(ws + 20035584);    // 153,600
    float* qssum     = (float*)(ws + 20189184);    // 896
    float* p2m_ws    = (float*)(ws + 20190080);    // 512,000
    u16*   pw2_ws    = (u16*)  (ws + 20702080);    // 76,800
    u16*   sw2_ws    = (u16*)  (ws + 20778880);    // 1,536,000
    u16*   cat_ws    = (u16*)  (ws + 22314880);    // 1,228,800
    u16*   g1_ws     = (u16*)  (ws + 23543680);    // 8,060,928
    float* part_ws   = (float*)(ws + 31604608);    // 4,915,200
    u16*   pwt_ws    = (u16*)  (ws + 36519808);    // 2,359,296
    u16*   qft_ws    = (u16*)  (ws + 38879104);    // 200*9*48*512*2 = 88,473,600
    // total 127,352,704 bytes

    k_convert3<<<2048, 256, 0, stream>>>(qemb, projw, relw1, A_all, projw_bf, relw1_bf);
    k_tileB<<<576, 256, 0, stream>>>(projw, pwt_ws);
    k_proto_shot<<<dim3(BNK_, 3), 256, 0, stream>>>(label, smask, semb, proto_shot);
    k_proto_mean<<<691, 256, 0, stream>>>(proto_shot, proto_f32, A_all);
    k_attn<<<BQ_, 256, 0, stream>>>(qemb, qmask, proto_f32, qft_ws, A_all + (size_t)R_SUP * D_,
                                    p2m_ws, qssum);
    k_qf<<<dim3(BQ_, 8), 256, 0, stream>>>(qemb, proto_f32, p2m_ws, qft_ws);
    k_gemm_gw<<<dim3(6, 50), 256, 0, stream>>>(A_all, projw_bf, g1_ws, sw2_ws, pw2_ws);
    k_gemm_q<<<1200, 256, 0, stream>>>(qft_ws, pwt_ws, projb, g1_ws, pw2_ws, sw2_ws,
                                       p2m_ws, qssum, cat_ws);
    k_relmlp<<<dim3(6, 4, 8), 256, 0, stream>>>(cat_ws, relw1_bf, part_ws);
    k_rel_fin<<<BQ_, 256, 0, stream>>>(part_ws, relb1, relw2, relb2, (float*)d_out);
}

// Round 17
// 460.113 us; speedup vs baseline: 1.3176x; 1.0498x over previous
//
#include <hip/hip_runtime.h>

typedef unsigned short u16;
typedef __attribute__((ext_vector_type(8))) short short8;
typedef __attribute__((ext_vector_type(4))) float f32x4;

#define B_   2
#define N_   5
#define K_   5
#define Q_   4
#define T_   5
#define D_   768
#define L_   128
#define BN_  (B_*N_)            // 10
#define BNK_ (B_*N_*K_)         // 50
#define BQ_  (B_*N_*Q_*N_)      // 200
#define K4_  (4*D_)             // 3072
#define KFQ  1536               // fuse K in main GEMM (chunks 2,3 only)
#define AROWS 144               // 128 query + 5 es + 11 pad

#define QEMB_N  (40*128*768)    // 3,932,160
#define PROJW_N (768*3072)      // 2,359,296
// A_all row map: [0,5120) qemb | [5120,5170) proto | [5170,5248) zero
//                [5248,6248) sup | [6248,6298) proto | [6298,6400) zero
#define R_PROTO1 5120
#define R_SUP    5248
#define R_PROTO2 6248

__device__ __forceinline__ float bf2f(u16 u) {
    return __uint_as_float(((unsigned)u) << 16);
}
__device__ __forceinline__ u16 f2bf(float f) {
    unsigned u = __float_as_uint(f);
    return (u16)((u + 0x7fffu + ((u >> 16) & 1u)) >> 16);
}
// async global->LDS, 16B per lane; lds base wave-uniform (HW adds lane*16)
__device__ __forceinline__ void gl_lds16(const u16* g, u16* l) {
    __builtin_amdgcn_global_load_lds(
        (const __attribute__((address_space(1))) unsigned int*)g,
        (__attribute__((address_space(3))) unsigned int*)l, 16, 0, 0);
}

// ---------------- K0: convert qemb (-> A_all rows 0..5119) / projw / relw1 ----------------
__global__ void k_convert3(const float* __restrict__ q, const float* __restrict__ pw,
                           const float* __restrict__ rw, u16* __restrict__ qo,
                           u16* __restrict__ po, u16* __restrict__ ro) {
    const long n1 = QEMB_N / 4, n2 = PROJW_N / 4;
    const long total = n1 + 2 * n2;
    for (long i = (long)blockIdx.x * 256 + threadIdx.x; i < total; i += (long)gridDim.x * 256) {
        const float* src; u16* dst; long k;
        if (i < n1)            { src = q;  dst = qo; k = i; }
        else if (i < n1 + n2)  { src = pw; dst = po; k = i - n1; }
        else                   { src = rw; dst = ro; k = i - n1 - n2; }
        float4 v = ((const float4*)src)[k];
        u16 o[4] = {f2bf(v.x), f2bf(v.y), f2bf(v.z), f2bf(v.w)};
        *(uint2*)(dst + k * 4) = *(const uint2*)o;
    }
}

// ---------------- K1: per-shot tag prototypes (segment-parallel) ----------------
__global__ void k_proto_shot(const float* __restrict__ label, const float* __restrict__ smask,
                             const float* __restrict__ semb, float* __restrict__ proto_shot) {
    int bnk = blockIdx.x;
    int s = blockIdx.y;                       // segment 0..2 (256 d's each)
    __shared__ int   s_tag[L_];
    __shared__ float s_w[L_];
    __shared__ float s_cnt[T_];
    int tid = threadIdx.x;
    if (tid < L_) {
        const float* lp = label + ((long)bnk * L_ + tid) * T_;
        float best = lp[0]; int bi = 0;
        #pragma unroll
        for (int t = 1; t < T_; ++t) { float v = lp[t]; if (v > best) { best = v; bi = t; } }
        s_tag[tid] = bi;
        s_w[tid]   = (bi == 0) ? smask[(long)bnk * L_ + tid] : 1.0f;
    }
    __syncthreads();
    if (tid < T_) {
        float c = 0.f;
        for (int l = 0; l < L_; ++l) if (s_tag[l] == tid) c += s_w[l];
        s_cnt[tid] = c;
    }
    __syncthreads();
    float acc[T_] = {};
    for (int l = 0; l < L_; ++l) {
        float w = s_w[l]; int tg = s_tag[l];
        float e = semb[((long)bnk * L_ + l) * D_ + tid + s * 256] * w;
        #pragma unroll
        for (int t = 0; t < T_; ++t) acc[t] += (tg == t) ? e : 0.0f;
    }
    int d = tid + s * 256;
    #pragma unroll
    for (int t = 0; t < T_; ++t) {
        float c = s_cnt[t];
        float v = (c > 0.f) ? acc[t] / fmaxf(c, 1.f) : 0.f;
        proto_shot[(bnk * T_ + t) * D_ + d] = v;
    }
}

// ---------------- K1b: mean over K shots -> proto_f32 + A_all proto rows + zero pads ----------------
__global__ void k_proto_mean(const float* __restrict__ proto_shot,
                             float* __restrict__ proto_f32, u16* __restrict__ A_all) {
    int bx = blockIdx.x;
    if (bx < 150) {
        int idx = bx * 256 + threadIdx.x;
        if (idx >= BN_ * T_ * D_) return;
        int r = idx / D_, d = idx - r * D_;
        int bn = r / T_;
        int rem = idx - bn * (T_ * D_);
        float s = 0.f;
        #pragma unroll
        for (int k = 0; k < K_; ++k) s += proto_shot[(bn * K_ + k) * (T_ * D_) + rem];
        s *= (1.f / K_);
        proto_f32[idx] = s;
        u16 b = f2bf(s);
        A_all[(size_t)(R_PROTO1 + r) * D_ + d] = b;
        A_all[(size_t)(R_PROTO2 + r) * D_ + d] = b;
    } else {
        // zero pad rows: [5170,5248) = 59904 elems, then [6298,6400) = 78336 elems
        int zidx = (bx - 150) * 256 + threadIdx.x;
        if (zidx >= 59904 + 78336) return;
        size_t off;
        if (zidx < 59904) off = (size_t)5170 * D_ + zidx;
        else              off = (size_t)6298 * D_ + (zidx - 59904);
        A_all[off] = 0;
    }
}

// ---------------- K2: co-attention -> qf (chunks 2,3), sup rows of A_all, p2m, qssum ----------------
__global__ void k_attn(const float* __restrict__ qemb, const float* __restrict__ qmask_g,
                       const float* __restrict__ proto_f32,
                       u16* __restrict__ qf, u16* __restrict__ supA,
                       float* __restrict__ p2m_ws, float* __restrict__ qssum_ws) {
    int x = blockIdx.x;
    int xcd = x & 7, slot = x >> 3;
    int g = (slot / 5) * 8 + xcd;           // q_idx 0..39
    int n2 = slot % 5;
    int bq = g * 5 + n2;
    int q_idx = g;
    int bn = (bq / (N_ * Q_ * N_)) * N_ + (bq % N_);
    __shared__ float s_proto[T_ * D_];
    __shared__ float s_att[T_][L_];
    __shared__ float s_ps[T_][L_];
    __shared__ float s_p2[L_][8];
    __shared__ float s_qm[L_];
    int tid = threadIdx.x;
    int w = tid >> 6, lane = tid & 63;
    for (int i = tid; i < T_ * D_; i += 256) s_proto[i] = proto_f32[bn * T_ * D_ + i];
    if (tid < L_) s_qm[tid] = qmask_g[(long)q_idx * L_ + tid];
    __syncthreads();
    for (int p = tid; p < T_ * L_; p += 256) {
        int t = p >> 7, q = p & (L_ - 1);
        const float* pp = s_proto + t * D_;
        const float4* qp = (const float4*)(qemb + ((size_t)q_idx * L_ + q) * D_);
        float acc = 0.f;
        #pragma unroll 4
        for (int d = 0; d < D_ / 4; ++d) {
            float4 v = qp[d];
            acc += v.x * pp[4 * d] + v.y * pp[4 * d + 1] + v.z * pp[4 * d + 2] + v.w * pp[4 * d + 3];
        }
        s_att[t][q] = acc + 100.f * s_qm[q];
    }
    __syncthreads();
    if (tid < T_) {                       // softmax over q (support path)
        int t = tid; float m = -1e30f;
        for (int q = 0; q < L_; ++q) m = fmaxf(m, s_att[t][q]);
        float ss = 0.f;
        for (int q = 0; q < L_; ++q) { float e = __expf(s_att[t][q] - m); s_ps[t][q] = e; ss += e; }
        float inv = 1.f / ss;
        for (int q = 0; q < L_; ++q) s_ps[t][q] *= inv;
    } else if (tid >= 128) {              // softmax over t (query path) -> masked weights
        int q = tid - 128; float m = -1e30f;
        float e[T_];
        #pragma unroll
        for (int t = 0; t < T_; ++t) m = fmaxf(m, s_att[t][q]);
        float ss = 0.f;
        #pragma unroll
        for (int t = 0; t < T_; ++t) { e[t] = __expf(s_att[t][q] - m); ss += e[t]; }
        float inv = s_qm[q] / ss;
        #pragma unroll
        for (int t = 0; t < T_; ++t) {
            s_p2[q][t] = e[t] * inv;
            p2m_ws[((size_t)bq * T_ + t) * L_ + q] = e[t] * inv;
        }
    } else if (tid == 5) {
        float s = 0.f;
        for (int q = 0; q < L_; ++q) s += s_qm[q];
        qssum_ws[bq] = s;
    }
    __syncthreads();
    u16* qfb = qf + (size_t)bq * AROWS * KFQ;
    {   // support_[t] -> A_all sup rows (bf16) + es rows 128..132 of qf (chunks 2,3)
        float acc[T_][3] = {};
        #pragma unroll 4
        for (int q = 0; q < L_; ++q) {
            const float* qp = qemb + ((size_t)q_idx * L_ + q) * D_;
            float qv[3];
            #pragma unroll
            for (int s = 0; s < 3; ++s) qv[s] = qp[tid + s * 256];
            #pragma unroll
            for (int t = 0; t < T_; ++t) {
                float p = s_ps[t][q];
                #pragma unroll
                for (int s = 0; s < 3; ++s) acc[t][s] += p * qv[s];
            }
        }
        #pragma unroll
        for (int t = 0; t < T_; ++t) {
            u16* er = qfb + (size_t)(128 + t) * KFQ;
            #pragma unroll
            for (int s = 0; s < 3; ++s) {
                int d = tid + s * 256;
                float p = s_proto[t * D_ + d];
                float sv = acc[t][s];
                supA[((size_t)bq * T_ + t) * D_ + d] = f2bf(sv);
                er[d]       = f2bf(fabsf(p - sv));
                er[768 + d] = f2bf(p * sv);
            }
        }
    }
    // query rows 0..127: wave per row; scalar lane-consecutive LDS reads (conflict-free),
    // coalesced 128B stores, zero barriers.
    for (int rr = 0; rr < 32; ++rr) {
        int row = w * 32 + rr;
        float p0 = s_p2[row][0], p1 = s_p2[row][1], p2v = s_p2[row][2];
        float p3 = s_p2[row][3], p4 = s_p2[row][4];
        const float* qrow = qemb + ((size_t)q_idx * L_ + row) * D_;
        u16* qr = qfb + (size_t)row * KFQ;
        #pragma unroll
        for (int ch = 0; ch < 12; ++ch) {
            int c = ch * 64 + lane;
            float m2 = p0 * s_proto[c] + p1 * s_proto[D_ + c] + p2v * s_proto[2 * D_ + c]
                     + p3 * s_proto[3 * D_ + c] + p4 * s_proto[4 * D_ + c];
            float qv = qrow[c];
            qr[c]       = f2bf(fabsf(qv - m2));
            qr[768 + c] = f2bf(qv * m2);
        }
    }
    {   // zero pad rows 133..143
        u16* pr2 = qfb + (size_t)133 * KFQ;
        short8 z = short8{0, 0, 0, 0, 0, 0, 0, 0};
        for (int i = tid; i < (11 * KFQ) / 8; i += 256) *(short8*)(pr2 + i * 8) = z;
    }
}

// ---------------- K3: combined G1+W2 GEMM: A_all(6400x768) @ projw(chunk0|chunk1)^T ----------------
// grid (6 j, 50 m). Blocks with mbase>=5248 use B chunk1 (offset 768). Proven dbuf BK64 loop.
#define SUBGW ((128 + 128) * 32)            // one 32-k sub-tile (A128+B128) in u16
__global__ __launch_bounds__(256) void k_gemm_gw(const u16* __restrict__ A_all,
                                                 const u16* __restrict__ projw_bf,
                                                 u16* __restrict__ g1, u16* __restrict__ sw2,
                                                 u16* __restrict__ pw2) {
    int mbase = blockIdx.y * 128;
    int jbase = blockIdx.x * 128;
    int boff = (mbase >= R_SUP) ? 768 : 0;
    __shared__ __align__(16) u16 sT[2][2 * SUBGW];
    int tid = threadIdx.x;
    int lane = tid & 63, w = tid >> 6, quad = lane >> 4, l16 = lane & 15;
    int srow = lane >> 2, sko = lane & 3;
    const u16* Ab = A_all + ((size_t)mbase + srow) * D_ + sko * 8;
    const u16* Bb = projw_bf + (size_t)(jbase + srow) * K4_ + boff + sko * 8;

    f32x4 zero = {0.f, 0.f, 0.f, 0.f};
    f32x4 acc[8][2];
    #pragma unroll
    for (int rt = 0; rt < 8; ++rt) { acc[rt][0] = zero; acc[rt][1] = zero; }

    auto issue = [&](int kt, int b) {
        #pragma unroll
        for (int s = 0; s < 2; ++s) {
            int k0 = kt * 64 + s * 32;
            u16* base = sT[b] + s * SUBGW;
            gl_lds16(Ab + (size_t)(w * 16) * D_ + k0, base + (w * 16) * 32);
            gl_lds16(Ab + (size_t)(64 + w * 16) * D_ + k0, base + (64 + w * 16) * 32);
            gl_lds16(Bb + (size_t)(w * 16) * K4_ + k0, base + (128 + w * 16) * 32);
            gl_lds16(Bb + (size_t)(64 + w * 16) * K4_ + k0, base + (128 + 64 + w * 16) * 32);
        }
    };

    issue(0, 0);
    for (int kt = 0; kt < D_ / 64; ++kt) {           // 12 iterations
        int cur = kt & 1;
        __syncthreads();
        if (kt + 1 < D_ / 64) issue(kt + 1, 1 - cur);
        #pragma unroll
        for (int s = 0; s < 2; ++s) {
            const u16* base = sT[cur] + s * SUBGW;
            short8 bfr[2];
            #pragma unroll
            for (int jj = 0; jj < 2; ++jj)
                bfr[jj] = *(const short8*)(base + (128 + (w * 2 + jj) * 16 + l16) * 32 + quad * 8);
            #pragma unroll
            for (int rt = 0; rt < 8; ++rt) {
                short8 a = *(const short8*)(base + (rt * 16 + l16) * 32 + quad * 8);
                acc[rt][0] = __builtin_amdgcn_mfma_f32_16x16x32_bf16(a, bfr[0], acc[rt][0], 0, 0, 0);
                acc[rt][1] = __builtin_amdgcn_mfma_f32_16x16x32_bf16(a, bfr[1], acc[rt][1], 0, 0, 0);
            }
        }
    }
    #pragma unroll
    for (int jj = 0; jj < 2; ++jj) {
        int col = jbase + (w * 2 + jj) * 16 + l16;
        #pragma unroll
        for (int rt = 0; rt < 8; ++rt)
            #pragma unroll
            for (int r = 0; r < 4; ++r) {
                int row = mbase + rt * 16 + quad * 4 + r;
                u16 v = f2bf(acc[rt][jj][r]);
                if (row < R_SUP)            g1[(size_t)row * D_ + col] = v;
                else if (row < R_PROTO2)    sw2[(size_t)(row - R_SUP) * D_ + col] = v;
                else if (row < R_PROTO2+50) pw2[(size_t)(row - R_PROTO2) * D_ + col] = v;
            }
    }
}

// ---------------- K4: main GEMM — j=128, BK=64, dbuf LDS (frozen best config) ----------------
#define SUBSZ ((AROWS + 128) * 32)          // one 32-k sub-tile (A+B) in u16
__global__ __launch_bounds__(256) void k_gemm_q(
        const u16* __restrict__ qf, const u16* __restrict__ projw_bf,
        const float* __restrict__ projb, const u16* __restrict__ g1,
        const u16* __restrict__ pw2, const u16* __restrict__ sw2,
        const float* __restrict__ p2m, const float* __restrict__ qssum_ws,
        u16* __restrict__ cat_ws) {
    int x = blockIdx.x;
    int xcd = x & 7, slot = x >> 3;          // slot 0..149
    int i = slot / 6, jslot = slot % 6;
    int g = (i / 5) * 8 + xcd;               // q-group 0..39, same map as k_attn
    int bq = g * 5 + (i % 5);
    int jbase = jslot * 128;
    int q_idx = bq / N_;
    int bn = (bq / (N_ * Q_ * N_)) * N_ + (bq % N_);
    __shared__ __align__(16) u16 sT[2][2 * SUBSZ];   // [buf][sub0|sub1]
    __shared__ float s_p2mL[T_ * 128];
    __shared__ float s_pw2L[T_ * 128];
    int tid = threadIdx.x;
    int lane = tid & 63, w = tid >> 6, quad = lane >> 4, l16 = lane & 15;
    int srow = lane >> 2, sko = lane & 3;
    const u16* Ab = qf + ((size_t)bq * AROWS + srow) * KFQ + sko * 8;
    const u16* Bb = projw_bf + (size_t)(jbase + srow) * K4_ + 1536 + sko * 8;

    f32x4 zero = {0.f, 0.f, 0.f, 0.f};
    f32x4 acc[9][2];
    #pragma unroll
    for (int rt = 0; rt < 9; ++rt) { acc[rt][0] = zero; acc[rt][1] = zero; }

    auto issue = [&](int kt, int b) {
        #pragma unroll
        for (int s = 0; s < 2; ++s) {
            int k0 = kt * 64 + s * 32;
            u16* base = sT[b] + s * SUBSZ;
            gl_lds16(Ab + (size_t)(w * 16) * KFQ + k0, base + (w * 16) * 32);
            gl_lds16(Ab + (size_t)(64 + w * 16) * KFQ + k0, base + (64 + w * 16) * 32);
            if (w == 0) gl_lds16(Ab + (size_t)128 * KFQ + k0, base + 128 * 32);
            gl_lds16(Bb + (size_t)(w * 16) * K4_ + k0, base + (AROWS + w * 16) * 32);
            gl_lds16(Bb + (size_t)(64 + w * 16) * K4_ + k0, base + (AROWS + 64 + w * 16) * 32);
        }
    };

    issue(0, 0);
    for (int kt = 0; kt < KFQ / 64; ++kt) {          // 24 iterations
        int cur = kt & 1;
        __syncthreads();
        if (kt + 1 < KFQ / 64) issue(kt + 1, 1 - cur);
        #pragma unroll
        for (int s = 0; s < 2; ++s) {
            const u16* base = sT[cur] + s * SUBSZ;
            short8 bfr[2];
            #pragma unroll
            for (int jj = 0; jj < 2; ++jj)
                bfr[jj] = *(const short8*)(base + (AROWS + (w * 2 + jj) * 16 + l16) * 32 + quad * 8);
            #pragma unroll
            for (int rt = 0; rt < 9; ++rt) {
                short8 a = *(const short8*)(base + (rt * 16 + l16) * 32 + quad * 8);
                acc[rt][0] = __builtin_amdgcn_mfma_f32_16x16x32_bf16(a, bfr[0], acc[rt][0], 0, 0, 0);
                acc[rt][1] = __builtin_amdgcn_mfma_f32_16x16x32_bf16(a, bfr[1], acc[rt][1], 0, 0, 0);
            }
        }
    }
    // epilogue staging: p2m + pw2 slices for this (bq, j) block
    for (int i2 = tid; i2 < T_ * 128; i2 += 256) {
        s_p2mL[i2] = p2m[(size_t)bq * (T_ * 128) + i2];
        s_pw2L[i2] = bf2f(pw2[(size_t)(bn * T_ + (i2 >> 7)) * D_ + jbase + (i2 & 127)]);
    }
    __syncthreads();
    float inv_qs = 1.f / qssum_ws[bq];
    #pragma unroll
    for (int jj = 0; jj < 2; ++jj) {
        int col = jbase + (w * 2 + jj) * 16 + l16;
        int cj = (w * 2 + jj) * 16 + l16;
        float bias = projb[col];
        float qmax = 0.f, qsum = 0.f, smax = 0.f, ssum = 0.f;
        #pragma unroll
        for (int rt = 0; rt < 8; ++rt) {
            #pragma unroll
            for (int r = 0; r < 4; ++r) {
                int row = rt * 16 + quad * 4 + r;
                float g1v = bf2f(g1[(size_t)(q_idx * 128 + row) * D_ + col]);
                float mix = s_p2mL[row] * s_pw2L[cj]
                          + s_p2mL[128 + row] * s_pw2L[128 + cj]
                          + s_p2mL[256 + row] * s_pw2L[256 + cj]
                          + s_p2mL[384 + row] * s_pw2L[384 + cj]
                          + s_p2mL[512 + row] * s_pw2L[512 + cj];
                float v = fmaxf(acc[rt][jj][r] + g1v + mix + bias, 0.f);
                qmax = fmaxf(qmax, v); qsum += v;
            }
        }
        #pragma unroll
        for (int r = 0; r < 4; ++r) {
            int t = quad * 4 + r;
            if (t < T_) {
                float g1v = bf2f(g1[(size_t)(5120 + bn * T_ + t) * D_ + col]);
                float s2v = bf2f(sw2[(size_t)(bq * T_ + t) * D_ + col]);
                float v = fmaxf(acc[8][jj][r] + g1v + s2v + bias, 0.f);
                smax = fmaxf(smax, v); ssum += v;
            }
        }
        qmax = fmaxf(qmax, __shfl_xor(qmax, 16, 64)); qmax = fmaxf(qmax, __shfl_xor(qmax, 32, 64));
        qsum += __shfl_xor(qsum, 16, 64);             qsum += __shfl_xor(qsum, 32, 64);
        smax = fmaxf(smax, __shfl_xor(smax, 16, 64)); smax = fmaxf(smax, __shfl_xor(smax, 32, 64));
        ssum += __shfl_xor(ssum, 16, 64);             ssum += __shfl_xor(ssum, 32, 64);
        if (quad == 0) {
            u16* cp = cat_ws + (size_t)bq * K4_;
            cp[col]           = f2bf(qmax);
            cp[D_ + col]      = f2bf(qsum * inv_qs);
            cp[2 * D_ + col]  = f2bf(smax);
            cp[3 * D_ + col]  = f2bf(ssum * 0.2f);
        }
    }
}

// ---------------- K5: relation MLP GEMM, split-K -> f32 partials ----------------
#define AST  40
__global__ __launch_bounds__(256) void k_relmlp(const u16* __restrict__ cat_ws,
                                                const u16* __restrict__ w1,
                                                float* __restrict__ part) {
    int mbase = blockIdx.y * 64;
    int jbase = blockIdx.x * 128;
    int ks = blockIdx.z;
    __shared__ __align__(16) u16 sA[64 * AST];
    __shared__ __align__(16) u16 sB[128 * AST];
    int tid = threadIdx.x;
    int lane = tid & 63, w = tid >> 6, quad = lane >> 4, l16 = lane & 15;
    f32x4 zero = {0.f, 0.f, 0.f, 0.f};
    f32x4 acc[4][2];
    #pragma unroll
    for (int rt = 0; rt < 4; ++rt) { acc[rt][0] = zero; acc[rt][1] = zero; }

    for (int kt = ks * 12; kt < ks * 12 + 12; ++kt) {
        int k0 = kt * 32;
        __syncthreads();
        {
            int row = tid >> 2, ko = (tid & 3) * 8;
            int grow = mbase + row;
            short8 val = short8{0, 0, 0, 0, 0, 0, 0, 0};
            if (grow < BQ_) val = *(const short8*)(cat_ws + (size_t)grow * K4_ + k0 + ko);
            *(short8*)(sA + row * AST + ko) = val;
        }
        for (int u = tid; u < 512; u += 256) {
            int row = u >> 2, ko = (u & 3) * 8;
            *(short8*)(sB + row * AST + ko) =
                *(const short8*)(w1 + (size_t)(jbase + row) * K4_ + k0 + ko);
        }
        __syncthreads();
        short8 af[4], bfr[2];
        #pragma unroll
        for (int rt = 0; rt < 4; ++rt)
            af[rt] = *(const short8*)(sA + (rt * 16 + l16) * AST + quad * 8);
        #pragma unroll
        for (int jj = 0; jj < 2; ++jj)
            bfr[jj] = *(const short8*)(sB + ((2 * w + jj) * 16 + l16) * AST + quad * 8);
        #pragma unroll
        for (int rt = 0; rt < 4; ++rt)
            #pragma unroll
            for (int jj = 0; jj < 2; ++jj)
                acc[rt][jj] = __builtin_amdgcn_mfma_f32_16x16x32_bf16(af[rt], bfr[jj], acc[rt][jj], 0, 0, 0);
    }
    #pragma unroll
    for (int jj = 0; jj < 2; ++jj) {
        int col = jbase + (2 * w + jj) * 16 + l16;
        #pragma unroll
        for (int rt = 0; rt < 4; ++rt) {
            #pragma unroll
            for (int r = 0; r < 4; ++r) {
                int grow = mbase + rt * 16 + quad * 4 + r;
                if (grow < BQ_)
                    part[((size_t)ks * BQ_ + grow) * D_ + col] = acc[rt][jj][r];
            }
        }
    }
}

// ---------------- K6: finish — sum partials, bias+relu, dot w2 ----------------
__global__ void k_rel_fin(const float* __restrict__ part, const float* __restrict__ b1,
                          const float* __restrict__ w2, const float* __restrict__ b2,
                          float* __restrict__ out) {
    int bq = blockIdx.x, tid = threadIdx.x;
    float a = 0.f;
    #pragma unroll
    for (int s = 0; s < 3; ++s) {
        int col = tid + s * 256;
        float sum = 0.f;
        #pragma unroll
        for (int ks = 0; ks < 8; ++ks) sum += part[((size_t)ks * BQ_ + bq) * D_ + col];
        float h = fmaxf(sum + b1[col], 0.f);
        a += h * w2[col];
    }
    __shared__ float red[256];
    red[tid] = a; __syncthreads();
    for (int off = 128; off >= 1; off >>= 1) {
        if (tid < off) red[tid] += red[tid + off];
        __syncthreads();
    }
    if (tid == 0) out[bq] = red[0] + b2[0];
}

extern "C" void kernel_launch(void* const* d_in, const int* in_sizes, int n_in,
                              void* d_out, int out_size, void* d_ws, size_t ws_size,
                              hipStream_t stream) {
    (void)in_sizes; (void)n_in; (void)out_size; (void)ws_size;
    const float* semb  = (const float*)d_in[0];
    const float* qemb  = (const float*)d_in[1];
    const float* smask = (const float*)d_in[2];
    const float* qmask = (const float*)d_in[3];
    const float* label = (const float*)d_in[4];
    const float* projw = (const float*)d_in[5];
    const float* projb = (const float*)d_in[6];
    const float* relw1 = (const float*)d_in[7];
    const float* relb1 = (const float*)d_in[8];
    const float* relw2 = (const float*)d_in[9];
    const float* relb2 = (const float*)d_in[10];

    char* ws = (char*)d_ws;
    u16*   A_all     = (u16*)  (ws + 0);           // 6400*768*2 = 9,830,400
    u16*   projw_bf  = (u16*)  (ws + 9830400);     // 4,718,592
    u16*   relw1_bf  = (u16*)  (ws + 14548992);    // 4,718,592
    float* proto_shot= (float*)(ws + 19267584);    // 768,000
    float* proto_f32 = (float*)(ws + 20035584);    // 153,600
    float* qssum     = (float*)(ws + 20189184);    // 896
    float* p2m_ws    = (float*)(ws + 20190080);    // 512,000
    u16*   pw2_ws    = (u16*)  (ws + 20702080);    // 76,800
    u16*   sw2_ws    = (u16*)  (ws + 20778880);    // 1,536,000
    u16*   cat_ws    = (u16*)  (ws + 22314880);    // 1,228,800
    u16*   g1_ws     = (u16*)  (ws + 23543680);    // 8,060,928
    float* part_ws   = (float*)(ws + 31604608);    // 4,915,200
    u16*   qf_ws     = (u16*)  (ws + 36519808);    // 88,473,600
    // total 124,993,408 bytes

    k_convert3<<<2048, 256, 0, stream>>>(qemb, projw, relw1, A_all, projw_bf, relw1_bf);
    k_proto_shot<<<dim3(BNK_, 3), 256, 0, stream>>>(label, smask, semb, proto_shot);
    k_proto_mean<<<691, 256, 0, stream>>>(proto_shot, proto_f32, A_all);
    k_attn<<<BQ_, 256, 0, stream>>>(qemb, qmask, proto_f32, qf_ws, A_all + (size_t)R_SUP * D_,
                                    p2m_ws, qssum);
    k_gemm_gw<<<dim3(6, 50), 256, 0, stream>>>(A_all, projw_bf, g1_ws, sw2_ws, pw2_ws);
    k_gemm_q<<<1200, 256, 0, stream>>>(qf_ws, projw_bf, projb, g1_ws, pw2_ws, sw2_ws,
                                       p2m_ws, qssum, cat_ws);
    k_relmlp<<<dim3(6, 4, 8), 256, 0, stream>>>(cat_ws, relw1_bf, part_ws);
    k_rel_fin<<<BQ_, 256, 0, stream>>>(part_ws, relb1, relw2, relb2, (float*)d_out);
}